// Round 9
// baseline (858.666 us; speedup 1.0000x reference)
//
#include <hip/hip_runtime.h>
#include <hip/hip_bf16.h>
#include <cstdint>

#define T_STEPS 250
#define BATCH   256
#define NI      700
#define NH      1024
#define NO      20
#define BETAF   0.9f
#define KPAD    704          // 22 * 32
#define KT_N    22
#define KCAT    2112         // 3 * KPAD

typedef __attribute__((ext_vector_type(8))) short bf16x8;
typedef __attribute__((ext_vector_type(4))) float f32x4;

static __device__ __forceinline__ unsigned short f2bu(float x) {
    union { __hip_bfloat16 h; unsigned short u; } c;
    c.h = __float2bfloat16(x);
    return c.u;
}
static __device__ __forceinline__ float b2f(unsigned short u) {
    union { __hip_bfloat16 h; unsigned short u; } c;
    c.u = u;
    return __bfloat162float(c.h);
}

// ---------------------------------------------------------------------------
// K0: zero LIF state; W2T[h][o]; Bcat = [hi|mid|lo] bf16 split of W1,
//     padded K 700->704. 3-split = 27 mantissa bits -> exact vs fp32.
// ---------------------------------------------------------------------------
__global__ __launch_bounds__(256) void k0_init(const float* __restrict__ W1,
                                               const float* __restrict__ W2,
                                               float* __restrict__ W2T,
                                               float* __restrict__ mem1,
                                               unsigned short* __restrict__ Bcat) {
    int idx = blockIdx.x * 256 + threadIdx.x;
    if (idx < BATCH * NH) mem1[idx] = 0.f;
    if (idx < NH * NO) {
        int h = idx / NO, o = idx % NO;
        W2T[idx] = W2[o * NH + h];
    }
    if (idx < NH * KPAD) {
        int n = idx / KPAD, k = idx % KPAD;
        float w = (k < NI) ? W1[n * NI + k] : 0.f;
        unsigned short hu = f2bu(w);
        float r1 = w - b2f(hu);
        unsigned short mu = f2bu(r1);
        float r2 = r1 - b2f(mu);
        unsigned short lu = f2bu(r2);
        unsigned short* row = Bcat + (size_t)n * KCAT + k;
        row[0]        = hu;
        row[KPAD]     = mu;
        row[2 * KPAD] = lu;
    }
}

// ---------------------------------------------------------------------------
// K1: convert fp32 binary spikes [rows][700] -> bf16 [rows][704] (exact).
// ---------------------------------------------------------------------------
__global__ __launch_bounds__(256) void k1_cvt(const float* __restrict__ A,
                                              unsigned short* __restrict__ Abf,
                                              int rows) {
    int idx = blockIdx.x * 256 + threadIdx.x;   // quad index: 176 per row
    int r = idx / 176, q = idx - r * 176;
    if (r >= rows) return;
    int k = q * 4;
    ushort4 o = make_ushort4(0, 0, 0, 0);
    if (k < NI) {
        float4 v = *(const float4*)(A + (size_t)r * NI + k);
        o.x = f2bu(v.x); o.y = f2bu(v.y); o.z = f2bu(v.z); o.w = f2bu(v.w);
    }
    *(ushort4*)(Abf + (size_t)r * KPAD + k) = o;
}

// ---------------------------------------------------------------------------
// K2: fc1 via bf16 MFMA, 3-way split — R4-PROVEN kernel, verbatim.
//   (269us / MfmaUtil 46 / 0 bank conflicts / 32KB LDS. Every pipelining
//   variant — R3 reg-stage, R5/R6 dbuf, R7 fp32-A, R8 counted-vmcnt —
//   regressed; implicit multi-block overlap at 4-5 blocks/CU wins.)
//   128x128 tile, BK=32, 4 waves, 48 MFMA / K-step.
//   LDS swizzle: phys 16B chunk p of row r holds logical p ^ ((r>>1)&3);
//   linear gload_lds dest + pre-swizzled per-lane source; swizzled read.
//   XCD-grouped bid swizzle: 8 n-tiles of one m-panel per XCD.
// ---------------------------------------------------------------------------
__global__ __launch_bounds__(256) void k2_fc1(const unsigned short* __restrict__ Abf,
                                              const unsigned short* __restrict__ Bcat,
                                              float* __restrict__ C) {
    __shared__ unsigned short As[128 * 32];
    __shared__ unsigned short Bs[3][128 * 32];
    const int tid  = threadIdx.x;
    const int lane = tid & 63;
    const int wv   = tid >> 6;

    int nwg = gridDim.x, bid = blockIdx.x, w;
    if ((nwg & 7) == 0) w = (bid & 7) * (nwg >> 3) + (bid >> 3);
    else                w = bid;
    const int brow = (w >> 3) * 128;
    const int bn   = (w & 7) * 128;
    const int wm   = (wv >> 1) * 64;
    const int wn   = (wv & 1) * 64;

    f32x4 acc[4][4];
#pragma unroll
    for (int i = 0; i < 4; ++i)
#pragma unroll
        for (int j = 0; j < 4; ++j) acc[i][j] = (f32x4){0.f, 0.f, 0.f, 0.f};

    auto stage = [&](const unsigned short* gbase, int rstride, int kcol,
                     unsigned short* lds) {
#pragma unroll
        for (int j = 0; j < 2; ++j) {
            int c   = wv * 128 + j * 64 + lane;
            int row = c >> 2;
            int lk  = ((c & 3) ^ ((row >> 1) & 3)) * 8;
            const unsigned short* src = gbase + (size_t)row * rstride + kcol + lk;
            __builtin_amdgcn_global_load_lds(
                (const __attribute__((address_space(1))) void*)src,
                (__attribute__((address_space(3))) void*)(lds + (wv * 128 + j * 64) * 8),
                16, 0, 0);
        }
    };

    const unsigned short* Ab = Abf + (size_t)brow * KPAD;
    const unsigned short* Bb = Bcat + (size_t)bn * KCAT;

    const int frow = lane & 15;
    const int fsl  = (((lane >> 4) & 3) ^ ((frow >> 1) & 3)) * 8;

    for (int kt = 0; kt < KT_N; ++kt) {
        stage(Ab, KPAD, kt * 32, As);
#pragma unroll
        for (int s = 0; s < 3; ++s)
            stage(Bb, KCAT, s * KPAD + kt * 32, Bs[s]);
        __syncthreads();

        bf16x8 a[4];
#pragma unroll
        for (int i = 0; i < 4; ++i)
            a[i] = *(const bf16x8*)&As[(wm + i * 16 + frow) * 32 + fsl];
#pragma unroll
        for (int s = 0; s < 3; ++s) {
#pragma unroll
            for (int j = 0; j < 4; ++j) {
                bf16x8 b = *(const bf16x8*)&Bs[s][(wn + j * 16 + frow) * 32 + fsl];
#pragma unroll
                for (int i = 0; i < 4; ++i)
                    acc[i][j] = __builtin_amdgcn_mfma_f32_16x16x32_bf16(a[i], b, acc[i][j], 0, 0, 0);
            }
        }
        __syncthreads();
    }

    // C/D layout: col = lane&15, row = (lane>>4)*4 + q
#pragma unroll
    for (int i = 0; i < 4; ++i) {
#pragma unroll
        for (int j = 0; j < 4; ++j) {
            int col  = bn + wn + j * 16 + (lane & 15);
            int row0 = brow + wm + i * 16 + ((lane >> 4) << 2);
#pragma unroll
            for (int q = 0; q < 4; ++q)
                C[(size_t)(row0 + q) * NH + col] = acc[i][j][q];
        }
    }
}

// ---------------------------------------------------------------------------
// K34: fused LIF scan + fc2. One block per batch element b; 4 waves x 256 h
//   each (thread handles h = wv*256 + j*64 + lane, j=0..3). Per t:
//   LIF in regs -> 4 ballots (uniform 64-bit masks) -> uniform ffs-gather
//   of W2T rows (~26 L2 loads, issued back-to-back; lanes 0..19 accumulate)
//   -> LDS reduce of 4 wave partials (2 barriers) -> cur2[t][b][0..19].
//   Depth-2 x 4-load prefetch of cur1 keeps ~8KB/CU in flight (~5.5 TB/s).
//   No bits buffer, no separate k4 dispatch.
// ---------------------------------------------------------------------------
__global__ __launch_bounds__(256) void k34_lif_fc2(const float* __restrict__ cur1,
                                                   float* __restrict__ mem1,
                                                   const float* __restrict__ W2T,
                                                   float* __restrict__ cur2,
                                                   int TC, int tg0) {
    __shared__ float part[3][NO];
    const int b    = blockIdx.x;
    const int wv   = threadIdx.x >> 6;
    const int lane = threadIdx.x & 63;
    const bool act = lane < NO;
    const int hb   = wv * 256;
    const size_t S = (size_t)BATCH * NH;
    const float* p = cur1 + (size_t)b * NH + hb + lane;
    float*      mp = mem1 + b * NH + hb + lane;
    const float* W = W2T + (act ? lane : 0);

    float m0 = mp[0], m1 = mp[64], m2 = mp[128], m3 = mp[192];

    auto ld = [&](int t, int j) -> float {
        int tt = t < TC ? t : TC - 1;          // clamp: always in-bounds
        return p[(size_t)tt * S + j * 64];
    };

#define K34_STEP(c0, c1, c2, c3, T)                                            \
    {                                                                          \
        float r0 = m0 > 1.f ? 1.f : 0.f;                                       \
        m0 = fmaf(BETAF, m0, (c0)) - r0;                                       \
        unsigned long long w0 = __ballot(m0 > 1.f);                            \
        float r1 = m1 > 1.f ? 1.f : 0.f;                                       \
        m1 = fmaf(BETAF, m1, (c1)) - r1;                                       \
        unsigned long long w1 = __ballot(m1 > 1.f);                            \
        float r2 = m2 > 1.f ? 1.f : 0.f;                                       \
        m2 = fmaf(BETAF, m2, (c2)) - r2;                                       \
        unsigned long long w2 = __ballot(m2 > 1.f);                            \
        float r3 = m3 > 1.f ? 1.f : 0.f;                                       \
        m3 = fmaf(BETAF, m3, (c3)) - r3;                                       \
        unsigned long long w3 = __ballot(m3 > 1.f);                            \
        float g0 = 0.f, g1 = 0.f;                                              \
        { unsigned long long m = w0;                                           \
          while (m) { int bt = __ffsll(m) - 1; m &= m - 1;                     \
                      g0 += W[(hb + bt) * NO]; } }                             \
        { unsigned long long m = w1;                                           \
          while (m) { int bt = __ffsll(m) - 1; m &= m - 1;                     \
                      g1 += W[(hb + 64 + bt) * NO]; } }                        \
        { unsigned long long m = w2;                                           \
          while (m) { int bt = __ffsll(m) - 1; m &= m - 1;                     \
                      g0 += W[(hb + 128 + bt) * NO]; } }                       \
        { unsigned long long m = w3;                                           \
          while (m) { int bt = __ffsll(m) - 1; m &= m - 1;                     \
                      g1 += W[(hb + 192 + bt) * NO]; } }                       \
        float g = g0 + g1;                                                     \
        if (wv != 0 && act) part[wv - 1][lane] = g;                            \
        __syncthreads();                                                       \
        if (wv == 0 && act)                                                    \
            cur2[((size_t)(tg0 + (T)) * BATCH + b) * NO + lane] =              \
                g + part[0][lane] + part[1][lane] + part[2][lane];             \
        __syncthreads();                                                       \
    }

    float a0 = ld(0, 0), a1 = ld(0, 1), a2 = ld(0, 2), a3 = ld(0, 3);
    float e0 = ld(1, 0), e1 = ld(1, 1), e2 = ld(1, 2), e3 = ld(1, 3);

    for (int t = 0; t < TC; t += 2) {
        K34_STEP(a0, a1, a2, a3, t);
        a0 = ld(t + 2, 0); a1 = ld(t + 2, 1);
        a2 = ld(t + 2, 2); a3 = ld(t + 2, 3);
        if (t + 1 < TC) {
            K34_STEP(e0, e1, e2, e3, t + 1);
            e0 = ld(t + 3, 0); e1 = ld(t + 3, 1);
            e2 = ld(t + 3, 2); e3 = ld(t + 3, 3);
        }
    }
#undef K34_STEP
    mp[0] = m0; mp[64] = m1; mp[128] = m2; mp[192] = m3;
}

// ---------------------------------------------------------------------------
// K5: leaky readout + softmax (no max-subtract; |mem| bounded), prefetch.
// ---------------------------------------------------------------------------
__global__ __launch_bounds__(256) void k5_readout(const float* __restrict__ cur2,
                                                  float* __restrict__ out_mem,
                                                  float* __restrict__ out_sm) {
    int b = blockIdx.x * 8 + (threadIdx.x >> 5);
    int o = threadIdx.x & 31;
    bool act = o < NO;
    const float* p = cur2 + (size_t)b * NO + (act ? o : 0);
    float mem = 0.f;
    float nxt = p[0];
    for (int t = 0; t < T_STEPS; ++t) {
        float c = nxt;
        if (t + 1 < T_STEPS) nxt = p[(size_t)(t + 1) * BATCH * NO];
        mem = fmaf(BETAF, mem, c);
        float e = act ? __expf(mem) : 0.f;
        float s = e;
#pragma unroll
        for (int off = 16; off; off >>= 1) s += __shfl_xor(s, off, 32);
        if (act) {
            int base = (t * BATCH + b) * NO;
            out_mem[base + o] = mem;
            out_sm[base + o] = __fdividef(e, s);
        }
    }
}

// ---------------------------------------------------------------------------
extern "C" void kernel_launch(void* const* d_in, const int* in_sizes, int n_in,
                              void* d_out, int out_size, void* d_ws, size_t ws_size,
                              hipStream_t stream) {
    const float* spikes = (const float*)d_in[0];   // [250,256,700]
    const float* W1     = (const float*)d_in[1];   // [1024,700]
    const float* W2     = (const float*)d_in[2];   // [20,1024]
    float* out_mem = (float*)d_out;                              // [250,256,20]
    float* out_sm  = out_mem + (size_t)T_STEPS * BATCH * NO;     // [250,256,20]

    char* ws = (char*)d_ws;
    size_t off = 0;
    auto alloc = [&](size_t bytes) -> char* {
        off = (off + 255) & ~(size_t)255;
        char* p = ws + off;
        off += bytes;
        return p;
    };
    float*          W2T  = (float*)alloc((size_t)NH * NO * 4);
    float*          mem1 = (float*)alloc((size_t)BATCH * NH * 4);
    float*          cur2 = (float*)alloc((size_t)T_STEPS * BATCH * NO * 4);
    unsigned short* Bcat = (unsigned short*)alloc((size_t)NH * KCAT * 2);

    // T-chunking: per step need cur1 (1 MB) + Abf (352 KB).
    size_t fixed = (off + 255) & ~(size_t)255;
    size_t rem = ws_size > fixed ? ws_size - fixed : 0;
    size_t per_t = (size_t)BATCH * NH * 4 + (size_t)BATCH * KPAD * 2 + 768;
    int TC = (int)(rem / per_t);
    if (TC > T_STEPS) TC = T_STEPS;
    if (TC < 1) TC = 1;
    float*          cur1 = (float*)alloc((size_t)TC * BATCH * NH * 4);
    unsigned short* Abf  = (unsigned short*)alloc((size_t)TC * BATCH * KPAD * 2);

    k0_init<<<(NH * KPAD + 255) / 256, 256, 0, stream>>>(W1, W2, W2T, mem1, Bcat);

    for (int t0 = 0; t0 < T_STEPS; t0 += TC) {
        int tc = T_STEPS - t0 < TC ? T_STEPS - t0 : TC;
        int rows = tc * BATCH;
        k1_cvt<<<(rows * 176 + 255) / 256, 256, 0, stream>>>(
            spikes + (size_t)t0 * BATCH * NI, Abf, rows);
        int nwg = (rows / 128) * 8;
        k2_fc1<<<nwg, 256, 0, stream>>>(Abf, Bcat, cur1);
        k34_lif_fc2<<<BATCH, 256, 0, stream>>>(cur1, mem1, W2T, cur2, tc, t0);
    }

    k5_readout<<<32, 256, 0, stream>>>(cur2, out_mem, out_sm);
}

// Round 11
// 533.259 us; speedup vs baseline: 1.6102x; 1.6102x over previous
//
#include <hip/hip_runtime.h>
#include <hip/hip_bf16.h>
#include <cstdint>

#define T_STEPS 250
#define BATCH   256
#define NI      700
#define NH      1024
#define NO      20
#define BETAF   0.9f
#define KPAD    704          // 22 * 32
#define KT_N    22
#define KCAT    2112         // 3 * KPAD

typedef __attribute__((ext_vector_type(8))) short bf16x8;
typedef __attribute__((ext_vector_type(4))) float f32x4;

static __device__ __forceinline__ unsigned short f2bu(float x) {
    union { __hip_bfloat16 h; unsigned short u; } c;
    c.h = __float2bfloat16(x);
    return c.u;
}
static __device__ __forceinline__ float b2f(unsigned short u) {
    union { __hip_bfloat16 h; unsigned short u; } c;
    c.u = u;
    return __bfloat162float(c.h);
}

// ---------------------------------------------------------------------------
// K0: zero LIF state; W2T[h][o]; Bcat = [hi|mid|lo] bf16 split of W1,
//     padded K 700->704. 3-split = 27 mantissa bits; ONLY this decomposition
//     has measured-pass evidence (absmax 0.0078, 6 rounds) — i8 4-plane
//     (R10) flipped a spike and failed. Do not change cur1 arithmetic.
// ---------------------------------------------------------------------------
__global__ __launch_bounds__(256) void k0_init(const float* __restrict__ W1,
                                               const float* __restrict__ W2,
                                               float* __restrict__ W2T,
                                               float* __restrict__ mem1,
                                               unsigned short* __restrict__ Bcat) {
    int idx = blockIdx.x * 256 + threadIdx.x;
    if (idx < BATCH * NH) mem1[idx] = 0.f;
    if (idx < NH * NO) {
        int h = idx / NO, o = idx % NO;
        W2T[idx] = W2[o * NH + h];
    }
    if (idx < NH * KPAD) {
        int n = idx / KPAD, k = idx % KPAD;
        float w = (k < NI) ? W1[n * NI + k] : 0.f;
        unsigned short hu = f2bu(w);
        float r1 = w - b2f(hu);
        unsigned short mu = f2bu(r1);
        float r2 = r1 - b2f(mu);
        unsigned short lu = f2bu(r2);
        unsigned short* row = Bcat + (size_t)n * KCAT + k;
        row[0]        = hu;
        row[KPAD]     = mu;
        row[2 * KPAD] = lu;
    }
}

// ---------------------------------------------------------------------------
// K1: convert fp32 binary spikes [rows][700] -> bf16 [rows][704] (exact).
// ---------------------------------------------------------------------------
__global__ __launch_bounds__(256) void k1_cvt(const float* __restrict__ A,
                                              unsigned short* __restrict__ Abf,
                                              int rows) {
    int idx = blockIdx.x * 256 + threadIdx.x;   // quad index: 176 per row
    int r = idx / 176, q = idx - r * 176;
    if (r >= rows) return;
    int k = q * 4;
    ushort4 o = make_ushort4(0, 0, 0, 0);
    if (k < NI) {
        float4 v = *(const float4*)(A + (size_t)r * NI + k);
        o.x = f2bu(v.x); o.y = f2bu(v.y); o.z = f2bu(v.z); o.w = f2bu(v.w);
    }
    *(ushort4*)(Abf + (size_t)r * KPAD + k) = o;
}

// ---------------------------------------------------------------------------
// K2: fc1 via bf16 MFMA, 3-way split — R4-PROVEN kernel, verbatim. LOCKED.
//   (269us / MfmaUtil 46 / 0 bank conflicts / 32KB LDS / 5 blocks/CU.
//   Failed variants: R3 reg-stage+early-loads 417; R5 dbuf64KB+fp32-A 444;
//   R6 dbuf64KB gload_lds 330; R7 fp32-A 128B-rows 405; R8 K-ext counted
//   vmcnt 356. Implicit multi-block overlap beats source pipelining here.)
//   128x128 tile, BK=32, 4 waves, 48 MFMA / K-step.
//   LDS swizzle: phys 16B chunk p of row r holds logical p ^ ((r>>1)&3);
//   linear gload_lds dest + pre-swizzled per-lane source; swizzled read.
//   XCD-grouped bid swizzle: 8 n-tiles of one m-panel per XCD.
// ---------------------------------------------------------------------------
__global__ __launch_bounds__(256) void k2_fc1(const unsigned short* __restrict__ Abf,
                                              const unsigned short* __restrict__ Bcat,
                                              float* __restrict__ C) {
    __shared__ unsigned short As[128 * 32];
    __shared__ unsigned short Bs[3][128 * 32];
    const int tid  = threadIdx.x;
    const int lane = tid & 63;
    const int wv   = tid >> 6;

    int nwg = gridDim.x, bid = blockIdx.x, w;
    if ((nwg & 7) == 0) w = (bid & 7) * (nwg >> 3) + (bid >> 3);
    else                w = bid;
    const int brow = (w >> 3) * 128;
    const int bn   = (w & 7) * 128;
    const int wm   = (wv >> 1) * 64;
    const int wn   = (wv & 1) * 64;

    f32x4 acc[4][4];
#pragma unroll
    for (int i = 0; i < 4; ++i)
#pragma unroll
        for (int j = 0; j < 4; ++j) acc[i][j] = (f32x4){0.f, 0.f, 0.f, 0.f};

    auto stage = [&](const unsigned short* gbase, int rstride, int kcol,
                     unsigned short* lds) {
#pragma unroll
        for (int j = 0; j < 2; ++j) {
            int c   = wv * 128 + j * 64 + lane;
            int row = c >> 2;
            int lk  = ((c & 3) ^ ((row >> 1) & 3)) * 8;
            const unsigned short* src = gbase + (size_t)row * rstride + kcol + lk;
            __builtin_amdgcn_global_load_lds(
                (const __attribute__((address_space(1))) void*)src,
                (__attribute__((address_space(3))) void*)(lds + (wv * 128 + j * 64) * 8),
                16, 0, 0);
        }
    };

    const unsigned short* Ab = Abf + (size_t)brow * KPAD;
    const unsigned short* Bb = Bcat + (size_t)bn * KCAT;

    const int frow = lane & 15;
    const int fsl  = (((lane >> 4) & 3) ^ ((frow >> 1) & 3)) * 8;

    for (int kt = 0; kt < KT_N; ++kt) {
        stage(Ab, KPAD, kt * 32, As);
#pragma unroll
        for (int s = 0; s < 3; ++s)
            stage(Bb, KCAT, s * KPAD + kt * 32, Bs[s]);
        __syncthreads();

        bf16x8 a[4];
#pragma unroll
        for (int i = 0; i < 4; ++i)
            a[i] = *(const bf16x8*)&As[(wm + i * 16 + frow) * 32 + fsl];
#pragma unroll
        for (int s = 0; s < 3; ++s) {
#pragma unroll
            for (int j = 0; j < 4; ++j) {
                bf16x8 b = *(const bf16x8*)&Bs[s][(wn + j * 16 + frow) * 32 + fsl];
#pragma unroll
                for (int i = 0; i < 4; ++i)
                    acc[i][j] = __builtin_amdgcn_mfma_f32_16x16x32_bf16(a[i], b, acc[i][j], 0, 0, 0);
            }
        }
        __syncthreads();
    }

    // C/D layout: col = lane&15, row = (lane>>4)*4 + q
#pragma unroll
    for (int i = 0; i < 4; ++i) {
#pragma unroll
        for (int j = 0; j < 4; ++j) {
            int col  = bn + wn + j * 16 + (lane & 15);
            int row0 = brow + wm + i * 16 + ((lane >> 4) << 2);
#pragma unroll
            for (int q = 0; q < 4; ++q)
                C[(size_t)(row0 + q) * NH + col] = acc[i][j][q];
        }
    }
}

// ---------------------------------------------------------------------------
// K3: LIF scan, 4-deep explicit prefetch (named regs, static indexing).
// ---------------------------------------------------------------------------
__global__ __launch_bounds__(256) void k3_lif(const float* __restrict__ cur1,
                                              float* __restrict__ mem1,
                                              unsigned long long* __restrict__ bits,
                                              int TC) {
    int b = blockIdx.x >> 2;
    int hg = blockIdx.x & 3;
    int h = hg * 256 + threadIdx.x;
    const size_t S = (size_t)BATCH * NH;
    const float* p = cur1 + (size_t)b * NH + h;
    unsigned long long* bp = bits + (size_t)b * 16 + hg * 4 + (threadIdx.x >> 6);
    const bool lead = (threadIdx.x & 63) == 0;
    float mem = mem1[b * NH + h];

#define LIF_STEP(cv, t)                                                        \
    {                                                                          \
        float reset = (mem > 1.0f) ? 1.0f : 0.0f;                              \
        mem = fmaf(BETAF, mem, (cv)) - reset;                                  \
        unsigned long long mk = __ballot(mem > 1.0f);                          \
        if (lead) bp[(size_t)(t) * (BATCH * 16)] = mk;                         \
    }

    float c0 = (0 < TC) ? p[0] : 0.f;
    float c1 = (1 < TC) ? p[S] : 0.f;
    float c2 = (2 < TC) ? p[2 * S] : 0.f;
    float c3 = (3 < TC) ? p[3 * S] : 0.f;
    int tc = 0;
    for (; tc + 4 <= TC; tc += 4) {
        LIF_STEP(c0, tc + 0); if (tc + 4 < TC) c0 = p[(size_t)(tc + 4) * S];
        LIF_STEP(c1, tc + 1); if (tc + 5 < TC) c1 = p[(size_t)(tc + 5) * S];
        LIF_STEP(c2, tc + 2); if (tc + 6 < TC) c2 = p[(size_t)(tc + 6) * S];
        LIF_STEP(c3, tc + 3); if (tc + 7 < TC) c3 = p[(size_t)(tc + 7) * S];
    }
    for (; tc < TC; ++tc) { float c = p[(size_t)tc * S]; LIF_STEP(c, tc); }
#undef LIF_STEP
    mem1[b * NH + h] = mem;
}

// ---------------------------------------------------------------------------
// K4: fc2 sparse gather, wave-parallel: one block per (t,b) row, 4 waves x
//     4 mask words each, 2-wide dual chains, LDS combine.
// ---------------------------------------------------------------------------
__global__ __launch_bounds__(256) void k4_fc2(const unsigned long long* __restrict__ bits,
                                              const float* __restrict__ W2T,
                                              float* __restrict__ cur2) {
    __shared__ float part[4][NO];
    int row  = blockIdx.x;
    int wv   = threadIdx.x >> 6;
    int lane = threadIdx.x & 63;
    bool act = lane < NO;
    unsigned long long mv = (lane < 4) ? bits[(size_t)row * 16 + wv * 4 + lane] : 0ULL;
    const float* W = W2T + (act ? lane : 0);
    float p0 = 0.f, p1 = 0.f;
#pragma unroll
    for (int i = 0; i < 4; ++i) {
        unsigned long long m = __shfl(mv, i);
        int base = (wv * 4 + i) * 64;
        while (m) {
            int  b0 = __ffsll(m) - 1;            m &= m - 1;
            bool v1 = m != 0;
            int  b1 = v1 ? __ffsll(m) - 1 : 0;   m &= m - 1;
            float w0 = W[(base + b0) * NO];
            float w1 = W[(base + b1) * NO];
            p0 += w0;
            p1 += v1 ? w1 : 0.f;
        }
    }
    float p = p0 + p1;
    if (wv != 0 && act) part[wv][lane] = p;
    __syncthreads();
    if (wv == 0 && act) {
        p += part[1][lane] + part[2][lane] + part[3][lane];
        cur2[(size_t)row * NO + lane] = p;
    }
}

// ---------------------------------------------------------------------------
// K5: leaky readout + softmax (no max-subtract; |mem| bounded), prefetch.
// ---------------------------------------------------------------------------
__global__ __launch_bounds__(256) void k5_readout(const float* __restrict__ cur2,
                                                  float* __restrict__ out_mem,
                                                  float* __restrict__ out_sm) {
    int b = blockIdx.x * 8 + (threadIdx.x >> 5);
    int o = threadIdx.x & 31;
    bool act = o < NO;
    const float* p = cur2 + (size_t)b * NO + (act ? o : 0);
    float mem = 0.f;
    float nxt = p[0];
    for (int t = 0; t < T_STEPS; ++t) {
        float c = nxt;
        if (t + 1 < T_STEPS) nxt = p[(size_t)(t + 1) * BATCH * NO];
        mem = fmaf(BETAF, mem, c);
        float e = act ? __expf(mem) : 0.f;
        float s = e;
#pragma unroll
        for (int off = 16; off; off >>= 1) s += __shfl_xor(s, off, 32);
        if (act) {
            int base = (t * BATCH + b) * NO;
            out_mem[base + o] = mem;
            out_sm[base + o] = __fdividef(e, s);
        }
    }
}

// ---------------------------------------------------------------------------
extern "C" void kernel_launch(void* const* d_in, const int* in_sizes, int n_in,
                              void* d_out, int out_size, void* d_ws, size_t ws_size,
                              hipStream_t stream) {
    const float* spikes = (const float*)d_in[0];   // [250,256,700]
    const float* W1     = (const float*)d_in[1];   // [1024,700]
    const float* W2     = (const float*)d_in[2];   // [20,1024]
    float* out_mem = (float*)d_out;                              // [250,256,20]
    float* out_sm  = out_mem + (size_t)T_STEPS * BATCH * NO;     // [250,256,20]

    char* ws = (char*)d_ws;
    size_t off = 0;
    auto alloc = [&](size_t bytes) -> char* {
        off = (off + 255) & ~(size_t)255;
        char* p = ws + off;
        off += bytes;
        return p;
    };
    float*          W2T  = (float*)alloc((size_t)NH * NO * 4);
    float*          mem1 = (float*)alloc((size_t)BATCH * NH * 4);
    float*          cur2 = (float*)alloc((size_t)T_STEPS * BATCH * NO * 4);
    unsigned short* Bcat = (unsigned short*)alloc((size_t)NH * KCAT * 2);

    // T-chunking: per step need cur1 (1 MB) + Abf (352 KB) + bits (32 KB).
    size_t fixed = (off + 255) & ~(size_t)255;
    size_t rem = ws_size > fixed ? ws_size - fixed : 0;
    size_t per_t = (size_t)BATCH * NH * 4 + (size_t)BATCH * KPAD * 2
                 + (size_t)BATCH * 16 * 8 + 768;
    int TC = (int)(rem / per_t);
    if (TC > T_STEPS) TC = T_STEPS;
    if (TC < 1) TC = 1;
    float*              cur1 = (float*)alloc((size_t)TC * BATCH * NH * 4);
    unsigned short*     Abf  = (unsigned short*)alloc((size_t)TC * BATCH * KPAD * 2);
    unsigned long long* bits = (unsigned long long*)alloc((size_t)TC * BATCH * 16 * 8);

    k0_init<<<(NH * KPAD + 255) / 256, 256, 0, stream>>>(W1, W2, W2T, mem1, Bcat);

    for (int t0 = 0; t0 < T_STEPS; t0 += TC) {
        int tc = T_STEPS - t0 < TC ? T_STEPS - t0 : TC;
        int rows = tc * BATCH;
        k1_cvt<<<(rows * 176 + 255) / 256, 256, 0, stream>>>(
            spikes + (size_t)t0 * BATCH * NI, Abf, rows);
        int nwg = (rows / 128) * 8;
        k2_fc1<<<nwg, 256, 0, stream>>>(Abf, Bcat, cur1);
        k3_lif<<<1024, 256, 0, stream>>>(cur1, mem1, bits, tc);
        k4_fc2<<<rows, 256, 0, stream>>>(bits, W2T, cur2 + (size_t)t0 * BATCH * NO);
    }

    k5_readout<<<32, 256, 0, stream>>>(cur2, out_mem, out_sm);
}

// Round 12
// 521.004 us; speedup vs baseline: 1.6481x; 1.0235x over previous
//
#include <hip/hip_runtime.h>
#include <hip/hip_bf16.h>
#include <cstdint>

#define T_STEPS 250
#define BATCH   256
#define NI      700
#define NH      1024
#define NO      20
#define BETAF   0.9f
#define KPAD    704          // 22 * 32
#define KT_N    22
#define KCAT    2112         // 3 * KPAD

typedef __attribute__((ext_vector_type(8))) short bf16x8;
typedef __attribute__((ext_vector_type(4))) float f32x4;

static __device__ __forceinline__ unsigned short f2bu(float x) {
    union { __hip_bfloat16 h; unsigned short u; } c;
    c.h = __float2bfloat16(x);
    return c.u;
}
static __device__ __forceinline__ float b2f(unsigned short u) {
    union { __hip_bfloat16 h; unsigned short u; } c;
    c.u = u;
    return __bfloat162float(c.h);
}

// ---------------------------------------------------------------------------
// K0: zero LIF state; W2T[h][o]; Bcat = [hi|mid|lo] bf16 split of W1,
//     padded K 700->704. 3-split = 27 mantissa bits; ONLY this decomposition
//     has measured-pass evidence (absmax 0.0078, 7 rounds). LOCKED.
// ---------------------------------------------------------------------------
__global__ __launch_bounds__(256) void k0_init(const float* __restrict__ W1,
                                               const float* __restrict__ W2,
                                               float* __restrict__ W2T,
                                               float* __restrict__ mem1,
                                               unsigned short* __restrict__ Bcat) {
    int idx = blockIdx.x * 256 + threadIdx.x;
    if (idx < BATCH * NH) mem1[idx] = 0.f;
    if (idx < NH * NO) {
        int h = idx / NO, o = idx % NO;
        W2T[idx] = W2[o * NH + h];
    }
    if (idx < NH * KPAD) {
        int n = idx / KPAD, k = idx % KPAD;
        float w = (k < NI) ? W1[n * NI + k] : 0.f;
        unsigned short hu = f2bu(w);
        float r1 = w - b2f(hu);
        unsigned short mu = f2bu(r1);
        float r2 = r1 - b2f(mu);
        unsigned short lu = f2bu(r2);
        unsigned short* row = Bcat + (size_t)n * KCAT + k;
        row[0]        = hu;
        row[KPAD]     = mu;
        row[2 * KPAD] = lu;
    }
}

// ---------------------------------------------------------------------------
// K1: convert fp32 binary spikes [rows][700] -> bf16 [rows][704] (exact).
// ---------------------------------------------------------------------------
__global__ __launch_bounds__(256) void k1_cvt(const float* __restrict__ A,
                                              unsigned short* __restrict__ Abf,
                                              int rows) {
    int idx = blockIdx.x * 256 + threadIdx.x;   // quad index: 176 per row
    int r = idx / 176, q = idx - r * 176;
    if (r >= rows) return;
    int k = q * 4;
    ushort4 o = make_ushort4(0, 0, 0, 0);
    if (k < NI) {
        float4 v = *(const float4*)(A + (size_t)r * NI + k);
        o.x = f2bu(v.x); o.y = f2bu(v.y); o.z = f2bu(v.z); o.w = f2bu(v.w);
    }
    *(ushort4*)(Abf + (size_t)r * KPAD + k) = o;
}

// ---------------------------------------------------------------------------
// K2: fc1 via bf16 MFMA, 3-way split — R4-PROVEN kernel, verbatim. LOCKED.
//   (271us / MfmaUtil 46 / 0 bank conflicts / 32KB LDS. Failed variants:
//   R3 417, R5 444, R6 330, R7 405, R8 356 — implicit multi-block overlap
//   beats every source-pipelining attempt at this shape.)
// ---------------------------------------------------------------------------
__global__ __launch_bounds__(256) void k2_fc1(const unsigned short* __restrict__ Abf,
                                              const unsigned short* __restrict__ Bcat,
                                              float* __restrict__ C) {
    __shared__ unsigned short As[128 * 32];
    __shared__ unsigned short Bs[3][128 * 32];
    const int tid  = threadIdx.x;
    const int lane = tid & 63;
    const int wv   = tid >> 6;

    int nwg = gridDim.x, bid = blockIdx.x, w;
    if ((nwg & 7) == 0) w = (bid & 7) * (nwg >> 3) + (bid >> 3);
    else                w = bid;
    const int brow = (w >> 3) * 128;
    const int bn   = (w & 7) * 128;
    const int wm   = (wv >> 1) * 64;
    const int wn   = (wv & 1) * 64;

    f32x4 acc[4][4];
#pragma unroll
    for (int i = 0; i < 4; ++i)
#pragma unroll
        for (int j = 0; j < 4; ++j) acc[i][j] = (f32x4){0.f, 0.f, 0.f, 0.f};

    auto stage = [&](const unsigned short* gbase, int rstride, int kcol,
                     unsigned short* lds) {
#pragma unroll
        for (int j = 0; j < 2; ++j) {
            int c   = wv * 128 + j * 64 + lane;
            int row = c >> 2;
            int lk  = ((c & 3) ^ ((row >> 1) & 3)) * 8;
            const unsigned short* src = gbase + (size_t)row * rstride + kcol + lk;
            __builtin_amdgcn_global_load_lds(
                (const __attribute__((address_space(1))) void*)src,
                (__attribute__((address_space(3))) void*)(lds + (wv * 128 + j * 64) * 8),
                16, 0, 0);
        }
    };

    const unsigned short* Ab = Abf + (size_t)brow * KPAD;
    const unsigned short* Bb = Bcat + (size_t)bn * KCAT;

    const int frow = lane & 15;
    const int fsl  = (((lane >> 4) & 3) ^ ((frow >> 1) & 3)) * 8;

    for (int kt = 0; kt < KT_N; ++kt) {
        stage(Ab, KPAD, kt * 32, As);
#pragma unroll
        for (int s = 0; s < 3; ++s)
            stage(Bb, KCAT, s * KPAD + kt * 32, Bs[s]);
        __syncthreads();

        bf16x8 a[4];
#pragma unroll
        for (int i = 0; i < 4; ++i)
            a[i] = *(const bf16x8*)&As[(wm + i * 16 + frow) * 32 + fsl];
#pragma unroll
        for (int s = 0; s < 3; ++s) {
#pragma unroll
            for (int j = 0; j < 4; ++j) {
                bf16x8 b = *(const bf16x8*)&Bs[s][(wn + j * 16 + frow) * 32 + fsl];
#pragma unroll
                for (int i = 0; i < 4; ++i)
                    acc[i][j] = __builtin_amdgcn_mfma_f32_16x16x32_bf16(a[i], b, acc[i][j], 0, 0, 0);
            }
        }
        __syncthreads();
    }

    // C/D layout: col = lane&15, row = (lane>>4)*4 + q
#pragma unroll
    for (int i = 0; i < 4; ++i) {
#pragma unroll
        for (int j = 0; j < 4; ++j) {
            int col  = bn + wn + j * 16 + (lane & 15);
            int row0 = brow + wm + i * 16 + ((lane >> 4) << 2);
#pragma unroll
            for (int q = 0; q < 4; ++q)
                C[(size_t)(row0 + q) * NH + col] = acc[i][j][q];
        }
    }
}

// ---------------------------------------------------------------------------
// K3: LIF scan, 2 h per thread (float2 loads, halved issue count), 4-deep
//   prefetch. Spike words j-interleaved: wave (b, half, wv) covers 128 h;
//   word pair {w0,w1} at widx=(half*4+wv)*2+{0,1} holds spikes of
//   h = half*512 + wv*128 + 2*lane + {0,1}. One ulonglong2 store per t.
//   LIF arithmetic per h bit-identical to R11 -> spike bits unchanged.
//   Grid: 512 blocks (b*2 + half) x 256 threads.
// ---------------------------------------------------------------------------
__global__ __launch_bounds__(256) void k3_lif(const float* __restrict__ cur1,
                                              float* __restrict__ mem1,
                                              unsigned long long* __restrict__ bits,
                                              int TC) {
    const int b    = blockIdx.x >> 1;
    const int half = blockIdx.x & 1;
    const int wv   = threadIdx.x >> 6;
    const int lane = threadIdx.x & 63;
    const int h    = half * 512 + wv * 128 + lane * 2;
    const size_t S = (size_t)BATCH * NH;
    const float* p = cur1 + (size_t)b * NH + h;
    unsigned long long* bp = bits + (size_t)b * 16 + (half * 4 + wv) * 2;
    const bool lead = lane == 0;

    float2 mm = *(const float2*)(mem1 + b * NH + h);
    float m0 = mm.x, m1 = mm.y;

    auto ld = [&](int t) -> float2 {
        int tt = t < TC ? t : TC - 1;
        return *(const float2*)(p + (size_t)tt * S);
    };

#define K3_STEP(cv, t)                                                         \
    {                                                                          \
        float r0 = (m0 > 1.f) ? 1.f : 0.f;                                     \
        m0 = fmaf(BETAF, m0, (cv).x) - r0;                                     \
        float r1 = (m1 > 1.f) ? 1.f : 0.f;                                     \
        m1 = fmaf(BETAF, m1, (cv).y) - r1;                                     \
        unsigned long long w0 = __ballot(m0 > 1.f);                            \
        unsigned long long w1 = __ballot(m1 > 1.f);                            \
        if (lead) {                                                            \
            ulonglong2 v; v.x = w0; v.y = w1;                                  \
            *(ulonglong2*)(bp + (size_t)(t) * (BATCH * 16)) = v;               \
        }                                                                      \
    }

    float2 c0 = ld(0), c1 = ld(1), c2 = ld(2), c3 = ld(3);
    int tc = 0;
    for (; tc + 4 <= TC; tc += 4) {
        K3_STEP(c0, tc + 0); c0 = ld(tc + 4);
        K3_STEP(c1, tc + 1); c1 = ld(tc + 5);
        K3_STEP(c2, tc + 2); c2 = ld(tc + 6);
        K3_STEP(c3, tc + 3); c3 = ld(tc + 7);
    }
    for (; tc < TC; ++tc) { float2 c = ld(tc); K3_STEP(c, tc); }
#undef K3_STEP
    float2 mo; mo.x = m0; mo.y = m1;
    *(float2*)(mem1 + b * NH + h) = mo;
}

// ---------------------------------------------------------------------------
// K4: fc2 sparse gather, ONE WAVE per (t,b) row (no LDS, no barrier), 4 rows
//   per block -> grid rows/4 (4x lower dispatch pressure than R11). Word i
//   maps h = (i>>1)*128 + 2*bit + (i&1) (k3's j-interleaved format).
// ---------------------------------------------------------------------------
__global__ __launch_bounds__(256) void k4_fc2(const unsigned long long* __restrict__ bits,
                                              const float* __restrict__ W2T,
                                              float* __restrict__ cur2) {
    int row  = blockIdx.x * 4 + (threadIdx.x >> 6);
    int lane = threadIdx.x & 63;
    bool act = lane < NO;
    unsigned long long mv = (lane < 16) ? bits[(size_t)row * 16 + lane] : 0ULL;
    const float* W = W2T + (act ? lane : 0);
    float p0 = 0.f, p1 = 0.f;
#pragma unroll
    for (int i = 0; i < 16; ++i) {
        unsigned long long m = __shfl(mv, i);
        int base = (i >> 1) * 128 + (i & 1);
        while (m) {
            int  b0 = __ffsll(m) - 1;            m &= m - 1;
            bool v1 = m != 0;
            int  b1 = v1 ? __ffsll(m) - 1 : 0;   m &= m - 1;
            float w0 = W[(base + 2 * b0) * NO];
            float w1 = W[(base + 2 * b1) * NO];
            p0 += w0;
            p1 += v1 ? w1 : 0.f;
        }
    }
    if (act) cur2[(size_t)row * NO + lane] = p0 + p1;
}

// ---------------------------------------------------------------------------
// K5: leaky readout + softmax; 128 blocks x 64 threads (one 32-lane group
//   per batch element, 4x more CUs busy than R11's 32-block config).
// ---------------------------------------------------------------------------
__global__ __launch_bounds__(64) void k5_readout(const float* __restrict__ cur2,
                                                 float* __restrict__ out_mem,
                                                 float* __restrict__ out_sm) {
    int b = blockIdx.x * 2 + (threadIdx.x >> 5);
    int o = threadIdx.x & 31;
    bool act = o < NO;
    const float* p = cur2 + (size_t)b * NO + (act ? o : 0);
    float mem = 0.f;
    float nxt = p[0];
    for (int t = 0; t < T_STEPS; ++t) {
        float c = nxt;
        if (t + 1 < T_STEPS) nxt = p[(size_t)(t + 1) * BATCH * NO];
        mem = fmaf(BETAF, mem, c);
        float e = act ? __expf(mem) : 0.f;
        float s = e;
#pragma unroll
        for (int off = 16; off; off >>= 1) s += __shfl_xor(s, off, 32);
        if (act) {
            int base = (t * BATCH + b) * NO;
            out_mem[base + o] = mem;
            out_sm[base + o] = __fdividef(e, s);
        }
    }
}

// ---------------------------------------------------------------------------
extern "C" void kernel_launch(void* const* d_in, const int* in_sizes, int n_in,
                              void* d_out, int out_size, void* d_ws, size_t ws_size,
                              hipStream_t stream) {
    const float* spikes = (const float*)d_in[0];   // [250,256,700]
    const float* W1     = (const float*)d_in[1];   // [1024,700]
    const float* W2     = (const float*)d_in[2];   // [20,1024]
    float* out_mem = (float*)d_out;                              // [250,256,20]
    float* out_sm  = out_mem + (size_t)T_STEPS * BATCH * NO;     // [250,256,20]

    char* ws = (char*)d_ws;
    size_t off = 0;
    auto alloc = [&](size_t bytes) -> char* {
        off = (off + 255) & ~(size_t)255;
        char* p = ws + off;
        off += bytes;
        return p;
    };
    float*          W2T  = (float*)alloc((size_t)NH * NO * 4);
    float*          mem1 = (float*)alloc((size_t)BATCH * NH * 4);
    float*          cur2 = (float*)alloc((size_t)T_STEPS * BATCH * NO * 4);
    unsigned short* Bcat = (unsigned short*)alloc((size_t)NH * KCAT * 2);

    // T-chunking: per step need cur1 (1 MB) + Abf (352 KB) + bits (32 KB).
    size_t fixed = (off + 255) & ~(size_t)255;
    size_t rem = ws_size > fixed ? ws_size - fixed : 0;
    size_t per_t = (size_t)BATCH * NH * 4 + (size_t)BATCH * KPAD * 2
                 + (size_t)BATCH * 16 * 8 + 768;
    int TC = (int)(rem / per_t);
    if (TC > T_STEPS) TC = T_STEPS;
    if (TC < 1) TC = 1;
    float*              cur1 = (float*)alloc((size_t)TC * BATCH * NH * 4);
    unsigned short*     Abf  = (unsigned short*)alloc((size_t)TC * BATCH * KPAD * 2);
    unsigned long long* bits = (unsigned long long*)alloc((size_t)TC * BATCH * 16 * 8);

    k0_init<<<(NH * KPAD + 255) / 256, 256, 0, stream>>>(W1, W2, W2T, mem1, Bcat);

    for (int t0 = 0; t0 < T_STEPS; t0 += TC) {
        int tc = T_STEPS - t0 < TC ? T_STEPS - t0 : TC;
        int rows = tc * BATCH;
        k1_cvt<<<(rows * 176 + 255) / 256, 256, 0, stream>>>(
            spikes + (size_t)t0 * BATCH * NI, Abf, rows);
        int nwg = (rows / 128) * 8;
        k2_fc1<<<nwg, 256, 0, stream>>>(Abf, Bcat, cur1);
        k3_lif<<<512, 256, 0, stream>>>(cur1, mem1, bits, tc);
        k4_fc2<<<rows / 4, 256, 0, stream>>>(bits, W2T, cur2 + (size_t)t0 * BATCH * NO);
    }

    k5_readout<<<128, 64, 0, stream>>>(cur2, out_mem, out_sm);
}

// Round 13
// 520.721 us; speedup vs baseline: 1.6490x; 1.0005x over previous
//
#include <hip/hip_runtime.h>
#include <hip/hip_bf16.h>
#include <cstdint>

#define T_STEPS 250
#define BATCH   256
#define NI      700
#define NH      1024
#define NO      20
#define BETAF   0.9f
#define KPAD    704          // 22 * 32
#define KT_N    22
#define KCAT    2112         // 3 * KPAD

typedef __attribute__((ext_vector_type(8))) short bf16x8;
typedef __attribute__((ext_vector_type(4))) float f32x4;

static __device__ __forceinline__ unsigned short f2bu(float x) {
    union { __hip_bfloat16 h; unsigned short u; } c;
    c.h = __float2bfloat16(x);
    return c.u;
}
static __device__ __forceinline__ float b2f(unsigned short u) {
    union { __hip_bfloat16 h; unsigned short u; } c;
    c.u = u;
    return __bfloat162float(c.h);
}

// ---------------------------------------------------------------------------
// K0: zero LIF state; W2T[h][o]; Bcat = [hi|mid|lo] bf16 split of W1,
//     padded K 700->704. LOCKED (only decomposition with pass evidence).
// ---------------------------------------------------------------------------
__global__ __launch_bounds__(256) void k0_init(const float* __restrict__ W1,
                                               const float* __restrict__ W2,
                                               float* __restrict__ W2T,
                                               float* __restrict__ mem1,
                                               unsigned short* __restrict__ Bcat) {
    int idx = blockIdx.x * 256 + threadIdx.x;
    if (idx < BATCH * NH) mem1[idx] = 0.f;
    if (idx < NH * NO) {
        int h = idx / NO, o = idx % NO;
        W2T[idx] = W2[o * NH + h];
    }
    if (idx < NH * KPAD) {
        int n = idx / KPAD, k = idx % KPAD;
        float w = (k < NI) ? W1[n * NI + k] : 0.f;
        unsigned short hu = f2bu(w);
        float r1 = w - b2f(hu);
        unsigned short mu = f2bu(r1);
        float r2 = r1 - b2f(mu);
        unsigned short lu = f2bu(r2);
        unsigned short* row = Bcat + (size_t)n * KCAT + k;
        row[0]        = hu;
        row[KPAD]     = mu;
        row[2 * KPAD] = lu;
    }
}

// ---------------------------------------------------------------------------
// K1: convert fp32 binary spikes [rows][700] -> bf16 [rows][704] (exact).
// ---------------------------------------------------------------------------
__global__ __launch_bounds__(256) void k1_cvt(const float* __restrict__ A,
                                              unsigned short* __restrict__ Abf,
                                              int rows) {
    int idx = blockIdx.x * 256 + threadIdx.x;   // quad index: 176 per row
    int r = idx / 176, q = idx - r * 176;
    if (r >= rows) return;
    int k = q * 4;
    ushort4 o = make_ushort4(0, 0, 0, 0);
    if (k < NI) {
        float4 v = *(const float4*)(A + (size_t)r * NI + k);
        o.x = f2bu(v.x); o.y = f2bu(v.y); o.z = f2bu(v.z); o.w = f2bu(v.w);
    }
    *(ushort4*)(Abf + (size_t)r * KPAD + k) = o;
}

// ---------------------------------------------------------------------------
// K2 v2: 256x256 tile, BK=32, 8 waves (512 thr), 6-phase counted-vmcnt
//   schedule (m201-template adaptation). Per iter (K-tile kt, buf=kt&1):
//     ph1: stage A(kt+1) halves -> buf^1 | ds a(mh0), b0 | bar | 16 MFMA | bar
//     ph2: stage B0(kt+1)               | ds b1          | bar | 16 MFMA | bar
//     ph3: stage B1(kt+1)               | ds b2          | bar | 16 MFMA | bar
//     ph4: stage B2(kt+1)               | ds a(mh1)      | bar | 16 MFMA | bar
//     ph5:                                16 MFMA | bar
//     ph6:                                16 MFMA | vmcnt(0) | bar
//   Raw s_barriers do NOT drain vmcnt: stages issued ph1-4 have ~5 compute
//   phases of cover before the single end-of-iter drain (issue-early/
//   drain-late). Race-free: reads of buf^1 completed (compiler lgkmcnt)
//   before each wave's end-of-prev-iter barrier; stage issues follow it.
//   BIT-IDENTICAL cur1 vs R4 (271us kernel): per acc element the MFMA
//   sequence is (kt asc, s asc), same 16x16x32 ops, same operand values.
//   LDS 128KB: As[2][256x32] + Bs[2][3][256x32]. R4-proven 64B-row swizzle
//   (phys chunk p of row r = p ^ ((r>>1)&3); linear dest + pre-swz source).
//   XCD-grouped bid swizzle; staged bytes/MFMA 8x better than 128² (85 B).
// ---------------------------------------------------------------------------
__global__ __launch_bounds__(512) void k2_fc1(const unsigned short* __restrict__ Abf,
                                              const unsigned short* __restrict__ Bcat,
                                              float* __restrict__ C) {
    __shared__ unsigned short As[2][256 * 32];
    __shared__ unsigned short Bs[2][3][256 * 32];
    const int tid  = threadIdx.x;
    const int lane = tid & 63;
    const int wv   = tid >> 6;
    const int wr   = wv >> 2;        // 0..1: wave row-half (128 rows)
    const int wc   = wv & 3;         // 0..3: wave col-quarter (64 cols)

    int nwg = gridDim.x, bid = blockIdx.x, w;
    if ((nwg & 7) == 0) w = (bid & 7) * (nwg >> 3) + (bid >> 3);
    else                w = bid;
    const int brow = (w >> 2) * 256;
    const int bn   = (w & 3) * 256;

    f32x4 acc[8][4];
#pragma unroll
    for (int f = 0; f < 8; ++f)
#pragma unroll
        for (int j = 0; j < 4; ++j) acc[f][j] = (f32x4){0.f, 0.f, 0.f, 0.f};

    const unsigned short* Ab = Abf + (size_t)brow * KPAD;
    const unsigned short* Bb = Bcat + (size_t)bn * KCAT;

    // stage one half-tile (128 rows x 32 bf16 = 512 chunks, 1 gload/thread):
    // linear LDS dest (wave base + lane*16), per-lane pre-swizzled source.
    auto stageHalf = [&](const unsigned short* gbase, int rstride, int kcol,
                         int h, unsigned short* tile) {
        int c   = h * 512 + wv * 64 + lane;
        int row = c >> 2;
        int lk  = ((c & 3) ^ ((row >> 1) & 3)) * 8;
        const unsigned short* src = gbase + (size_t)row * rstride + kcol + lk;
        __builtin_amdgcn_global_load_lds(
            (const __attribute__((address_space(1))) void*)src,
            (__attribute__((address_space(3))) void*)(tile + (size_t)(h * 512 + wv * 64) * 8),
            16, 0, 0);
    };

    const int frow = lane & 15;
    const int fsl  = (((lane >> 4) & 3) ^ ((frow >> 1) & 3)) * 8;

    bf16x8 a[4], b0[4], b1[4], b2[4];
    auto loadA = [&](const unsigned short* Ac, int mh) {
#pragma unroll
        for (int i = 0; i < 4; ++i)
            a[i] = *(const bf16x8*)&Ac[(wr * 128 + mh * 64 + i * 16 + frow) * 32 + fsl];
    };
    auto loadB = [&](const unsigned short* Bc, bf16x8* b) {
#pragma unroll
        for (int j = 0; j < 4; ++j)
            b[j] = *(const bf16x8*)&Bc[(wc * 64 + j * 16 + frow) * 32 + fsl];
    };
    auto mm = [&](int mh, const bf16x8* b) {
        __builtin_amdgcn_s_setprio(1);
#pragma unroll
        for (int j = 0; j < 4; ++j)
#pragma unroll
            for (int i = 0; i < 4; ++i)
                acc[mh * 4 + i][j] = __builtin_amdgcn_mfma_f32_16x16x32_bf16(
                    a[i], b[j], acc[mh * 4 + i][j], 0, 0, 0);
        __builtin_amdgcn_s_setprio(0);
    };

    // prologue: stage K-tile 0 into buf0 (8 halves), full drain, barrier.
    stageHalf(Ab, KPAD, 0, 0, As[0]);
    stageHalf(Ab, KPAD, 0, 1, As[0]);
#pragma unroll
    for (int s = 0; s < 3; ++s) {
        stageHalf(Bb, KCAT, s * KPAD, 0, Bs[0][s]);
        stageHalf(Bb, KCAT, s * KPAD, 1, Bs[0][s]);
    }
    asm volatile("s_waitcnt vmcnt(0)" ::: "memory");
    __builtin_amdgcn_s_barrier();

    for (int kt = 0; kt < KT_N; ++kt) {
        const int buf = kt & 1;
        const unsigned short* Ac = As[buf];
        const unsigned short* B0 = Bs[buf][0];
        const unsigned short* B1 = Bs[buf][1];
        const unsigned short* B2 = Bs[buf][2];
        const bool st = (kt + 1 < KT_N);
        const int kc = (kt + 1) * 32;

        // ph1
        if (st) { stageHalf(Ab, KPAD, kc, 0, As[buf ^ 1]);
                  stageHalf(Ab, KPAD, kc, 1, As[buf ^ 1]); }
        loadA(Ac, 0);
        loadB(B0, b0);
        __builtin_amdgcn_s_barrier();
        mm(0, b0);
        __builtin_amdgcn_s_barrier();
        // ph2
        if (st) { stageHalf(Bb, KCAT, kc, 0, Bs[buf ^ 1][0]);
                  stageHalf(Bb, KCAT, kc, 1, Bs[buf ^ 1][0]); }
        loadB(B1, b1);
        __builtin_amdgcn_s_barrier();
        mm(0, b1);
        __builtin_amdgcn_s_barrier();
        // ph3
        if (st) { stageHalf(Bb, KCAT, KPAD + kc, 0, Bs[buf ^ 1][1]);
                  stageHalf(Bb, KCAT, KPAD + kc, 1, Bs[buf ^ 1][1]); }
        loadB(B2, b2);
        __builtin_amdgcn_s_barrier();
        mm(0, b2);
        __builtin_amdgcn_s_barrier();
        // ph4
        if (st) { stageHalf(Bb, KCAT, 2 * KPAD + kc, 0, Bs[buf ^ 1][2]);
                  stageHalf(Bb, KCAT, 2 * KPAD + kc, 1, Bs[buf ^ 1][2]); }
        loadA(Ac, 1);
        __builtin_amdgcn_s_barrier();
        mm(1, b0);
        __builtin_amdgcn_s_barrier();
        // ph5
        mm(1, b1);
        __builtin_amdgcn_s_barrier();
        // ph6
        mm(1, b2);
        if (st) asm volatile("s_waitcnt vmcnt(0)" ::: "memory");
        __builtin_amdgcn_s_barrier();
    }

    // C/D layout: col = lane&15, row = (lane>>4)*4 + q; acc[f] rows = f*16.
#pragma unroll
    for (int f = 0; f < 8; ++f) {
#pragma unroll
        for (int j = 0; j < 4; ++j) {
            int col  = bn + wc * 64 + j * 16 + (lane & 15);
            int row0 = brow + wr * 128 + f * 16 + ((lane >> 4) << 2);
#pragma unroll
            for (int q = 0; q < 4; ++q)
                C[(size_t)(row0 + q) * NH + col] = acc[f][j][q];
        }
    }
}

// ---------------------------------------------------------------------------
// K3: LIF scan, 2 h per thread (float2 loads), 4-deep prefetch,
//   j-interleaved spike words (R12-proven). Bit-identical LIF arithmetic.
// ---------------------------------------------------------------------------
__global__ __launch_bounds__(256) void k3_lif(const float* __restrict__ cur1,
                                              float* __restrict__ mem1,
                                              unsigned long long* __restrict__ bits,
                                              int TC) {
    const int b    = blockIdx.x >> 1;
    const int half = blockIdx.x & 1;
    const int wv   = threadIdx.x >> 6;
    const int lane = threadIdx.x & 63;
    const int h    = half * 512 + wv * 128 + lane * 2;
    const size_t S = (size_t)BATCH * NH;
    const float* p = cur1 + (size_t)b * NH + h;
    unsigned long long* bp = bits + (size_t)b * 16 + (half * 4 + wv) * 2;
    const bool lead = lane == 0;

    float2 mm = *(const float2*)(mem1 + b * NH + h);
    float m0 = mm.x, m1 = mm.y;

    auto ld = [&](int t) -> float2 {
        int tt = t < TC ? t : TC - 1;
        return *(const float2*)(p + (size_t)tt * S);
    };

#define K3_STEP(cv, t)                                                         \
    {                                                                          \
        float r0 = (m0 > 1.f) ? 1.f : 0.f;                                     \
        m0 = fmaf(BETAF, m0, (cv).x) - r0;                                     \
        float r1 = (m1 > 1.f) ? 1.f : 0.f;                                     \
        m1 = fmaf(BETAF, m1, (cv).y) - r1;                                     \
        unsigned long long w0 = __ballot(m0 > 1.f);                            \
        unsigned long long w1 = __ballot(m1 > 1.f);                            \
        if (lead) {                                                            \
            ulonglong2 v; v.x = w0; v.y = w1;                                  \
            *(ulonglong2*)(bp + (size_t)(t) * (BATCH * 16)) = v;               \
        }                                                                      \
    }

    float2 c0 = ld(0), c1 = ld(1), c2 = ld(2), c3 = ld(3);
    int tc = 0;
    for (; tc + 4 <= TC; tc += 4) {
        K3_STEP(c0, tc + 0); c0 = ld(tc + 4);
        K3_STEP(c1, tc + 1); c1 = ld(tc + 5);
        K3_STEP(c2, tc + 2); c2 = ld(tc + 6);
        K3_STEP(c3, tc + 3); c3 = ld(tc + 7);
    }
    for (; tc < TC; ++tc) { float2 c = ld(tc); K3_STEP(c, tc); }
#undef K3_STEP
    float2 mo; mo.x = m0; mo.y = m1;
    *(float2*)(mem1 + b * NH + h) = mo;
}

// ---------------------------------------------------------------------------
// K4: fc2 sparse gather, one wave per (t,b) row, 4 rows/block.
//   Word i maps h = (i>>1)*128 + 2*bit + (i&1).
// ---------------------------------------------------------------------------
__global__ __launch_bounds__(256) void k4_fc2(const unsigned long long* __restrict__ bits,
                                              const float* __restrict__ W2T,
                                              float* __restrict__ cur2) {
    int row  = blockIdx.x * 4 + (threadIdx.x >> 6);
    int lane = threadIdx.x & 63;
    bool act = lane < NO;
    unsigned long long mv = (lane < 16) ? bits[(size_t)row * 16 + lane] : 0ULL;
    const float* W = W2T + (act ? lane : 0);
    float p0 = 0.f, p1 = 0.f;
#pragma unroll
    for (int i = 0; i < 16; ++i) {
        unsigned long long m = __shfl(mv, i);
        int base = (i >> 1) * 128 + (i & 1);
        while (m) {
            int  b0 = __ffsll(m) - 1;            m &= m - 1;
            bool v1 = m != 0;
            int  b1 = v1 ? __ffsll(m) - 1 : 0;   m &= m - 1;
            float w0 = W[(base + 2 * b0) * NO];
            float w1 = W[(base + 2 * b1) * NO];
            p0 += w0;
            p1 += v1 ? w1 : 0.f;
        }
    }
    if (act) cur2[(size_t)row * NO + lane] = p0 + p1;
}

// ---------------------------------------------------------------------------
// K5: leaky readout + softmax; 128 blocks x 64 threads.
// ---------------------------------------------------------------------------
__global__ __launch_bounds__(64) void k5_readout(const float* __restrict__ cur2,
                                                 float* __restrict__ out_mem,
                                                 float* __restrict__ out_sm) {
    int b = blockIdx.x * 2 + (threadIdx.x >> 5);
    int o = threadIdx.x & 31;
    bool act = o < NO;
    const float* p = cur2 + (size_t)b * NO + (act ? o : 0);
    float mem = 0.f;
    float nxt = p[0];
    for (int t = 0; t < T_STEPS; ++t) {
        float c = nxt;
        if (t + 1 < T_STEPS) nxt = p[(size_t)(t + 1) * BATCH * NO];
        mem = fmaf(BETAF, mem, c);
        float e = act ? __expf(mem) : 0.f;
        float s = e;
#pragma unroll
        for (int off = 16; off; off >>= 1) s += __shfl_xor(s, off, 32);
        if (act) {
            int base = (t * BATCH + b) * NO;
            out_mem[base + o] = mem;
            out_sm[base + o] = __fdividef(e, s);
        }
    }
}

// ---------------------------------------------------------------------------
extern "C" void kernel_launch(void* const* d_in, const int* in_sizes, int n_in,
                              void* d_out, int out_size, void* d_ws, size_t ws_size,
                              hipStream_t stream) {
    const float* spikes = (const float*)d_in[0];   // [250,256,700]
    const float* W1     = (const float*)d_in[1];   // [1024,700]
    const float* W2     = (const float*)d_in[2];   // [20,1024]
    float* out_mem = (float*)d_out;                              // [250,256,20]
    float* out_sm  = out_mem + (size_t)T_STEPS * BATCH * NO;     // [250,256,20]

    char* ws = (char*)d_ws;
    size_t off = 0;
    auto alloc = [&](size_t bytes) -> char* {
        off = (off + 255) & ~(size_t)255;
        char* p = ws + off;
        off += bytes;
        return p;
    };
    float*          W2T  = (float*)alloc((size_t)NH * NO * 4);
    float*          mem1 = (float*)alloc((size_t)BATCH * NH * 4);
    float*          cur2 = (float*)alloc((size_t)T_STEPS * BATCH * NO * 4);
    unsigned short* Bcat = (unsigned short*)alloc((size_t)NH * KCAT * 2);

    // T-chunking: per step need cur1 (1 MB) + Abf (352 KB) + bits (32 KB).
    size_t fixed = (off + 255) & ~(size_t)255;
    size_t rem = ws_size > fixed ? ws_size - fixed : 0;
    size_t per_t = (size_t)BATCH * NH * 4 + (size_t)BATCH * KPAD * 2
                 + (size_t)BATCH * 16 * 8 + 768;
    int TC = (int)(rem / per_t);
    if (TC > T_STEPS) TC = T_STEPS;
    if (TC < 1) TC = 1;
    float*              cur1 = (float*)alloc((size_t)TC * BATCH * NH * 4);
    unsigned short*     Abf  = (unsigned short*)alloc((size_t)TC * BATCH * KPAD * 2);
    unsigned long long* bits = (unsigned long long*)alloc((size_t)TC * BATCH * 16 * 8);

    k0_init<<<(NH * KPAD + 255) / 256, 256, 0, stream>>>(W1, W2, W2T, mem1, Bcat);

    for (int t0 = 0; t0 < T_STEPS; t0 += TC) {
        int tc = T_STEPS - t0 < TC ? T_STEPS - t0 : TC;
        int rows = tc * BATCH;
        k1_cvt<<<(rows * 176 + 255) / 256, 256, 0, stream>>>(
            spikes + (size_t)t0 * BATCH * NI, Abf, rows);
        int nwg = (rows / 256) * 4;   // 256-row m-tiles x 4 n-tiles
        k2_fc1<<<nwg, 512, 0, stream>>>(Abf, Bcat, cur1);
        k3_lif<<<512, 256, 0, stream>>>(cur1, mem1, bits, tc);
        k4_fc2<<<rows / 4, 256, 0, stream>>>(bits, W2T, cur2 + (size_t)t0 * BATCH * NO);
    }

    k5_readout<<<128, 64, 0, stream>>>(cur2, out_mem, out_sm);
}

// Round 14
// 517.872 us; speedup vs baseline: 1.6581x; 1.0055x over previous
//
#include <hip/hip_runtime.h>
#include <hip/hip_bf16.h>
#include <cstdint>

#define T_STEPS 250
#define BATCH   256
#define NI      700
#define NH      1024
#define NO      20
#define BETAF   0.9f
#define KPAD    704          // 22 * 32
#define KT_N    22
#define KCAT    2112         // 3 * KPAD

typedef __attribute__((ext_vector_type(8))) short bf16x8;
typedef __attribute__((ext_vector_type(4))) float f32x4;

static __device__ __forceinline__ unsigned short f2bu(float x) {
    union { __hip_bfloat16 h; unsigned short u; } c;
    c.h = __float2bfloat16(x);
    return c.u;
}
static __device__ __forceinline__ float b2f(unsigned short u) {
    union { __hip_bfloat16 h; unsigned short u; } c;
    c.u = u;
    return __bfloat162float(c.h);
}

// ---------------------------------------------------------------------------
// K0: zero LIF state; W2T[h][o]; Bcat = [hi|mid|lo] bf16 split of W1,
//     padded K 700->704. LOCKED (only decomposition with pass evidence).
// ---------------------------------------------------------------------------
__global__ __launch_bounds__(256) void k0_init(const float* __restrict__ W1,
                                               const float* __restrict__ W2,
                                               float* __restrict__ W2T,
                                               float* __restrict__ mem1,
                                               unsigned short* __restrict__ Bcat) {
    int idx = blockIdx.x * 256 + threadIdx.x;
    if (idx < BATCH * NH) mem1[idx] = 0.f;
    if (idx < NH * NO) {
        int h = idx / NO, o = idx % NO;
        W2T[idx] = W2[o * NH + h];
    }
    if (idx < NH * KPAD) {
        int n = idx / KPAD, k = idx % KPAD;
        float w = (k < NI) ? W1[n * NI + k] : 0.f;
        unsigned short hu = f2bu(w);
        float r1 = w - b2f(hu);
        unsigned short mu = f2bu(r1);
        float r2 = r1 - b2f(mu);
        unsigned short lu = f2bu(r2);
        unsigned short* row = Bcat + (size_t)n * KCAT + k;
        row[0]        = hu;
        row[KPAD]     = mu;
        row[2 * KPAD] = lu;
    }
}

// ---------------------------------------------------------------------------
// K1: convert fp32 binary spikes [rows][700] -> bf16 [rows][704] (exact).
// ---------------------------------------------------------------------------
__global__ __launch_bounds__(256) void k1_cvt(const float* __restrict__ A,
                                              unsigned short* __restrict__ Abf,
                                              int rows) {
    int idx = blockIdx.x * 256 + threadIdx.x;   // quad index: 176 per row
    int r = idx / 176, q = idx - r * 176;
    if (r >= rows) return;
    int k = q * 4;
    ushort4 o = make_ushort4(0, 0, 0, 0);
    if (k < NI) {
        float4 v = *(const float4*)(A + (size_t)r * NI + k);
        o.x = f2bu(v.x); o.y = f2bu(v.y); o.z = f2bu(v.z); o.w = f2bu(v.w);
    }
    *(ushort4*)(Abf + (size_t)r * KPAD + k) = o;
}

// ---------------------------------------------------------------------------
// K2 v3: 256x256 / BK=32 / 8 waves / 6 phases — R13-passing kernel with the
//   end-of-iter vmcnt(0) replaced by a COUNTED WAIT LADDER (T4):
//   per-wave stage order per iter (8 loads): A×2@ph1 B0×2@ph2 B1×2@ph3 B2×2@ph4.
//   ph1: vmcnt(4) -> forces A,B0(cur) [issued 6 phases earlier]
//   ph2: vmcnt(4) -> forces B1(cur)   [outstanding: B2(cur)×2 + A(nxt)×2]
//   ph3: vmcnt(4) -> forces B2(cur)   [5 phases of cover vs R13's 2]
//   epilogue iter (no new stages): 4 / 2 / 0.  vmcnt(0) never in steady loop.
//   Wait precedes stage-issues + leading barrier (all-waves guarantee);
//   ds_reads of wait-covered regions follow the barrier (ph1-3); ph4's A-mh1
//   read is covered by ph1's wait so it stays pre-barrier. Same barriers,
//   same MFMA order (kt asc, s asc) -> cur1 BIT-IDENTICAL; absmax shift = race.
//   LDS 128KB, R4-proven 64B-row swizzle (0 conflicts), XCD bid swizzle.
// ---------------------------------------------------------------------------
__global__ __launch_bounds__(512) void k2_fc1(const unsigned short* __restrict__ Abf,
                                              const unsigned short* __restrict__ Bcat,
                                              float* __restrict__ C) {
    __shared__ unsigned short As[2][256 * 32];
    __shared__ unsigned short Bs[2][3][256 * 32];
    const int tid  = threadIdx.x;
    const int lane = tid & 63;
    const int wv   = tid >> 6;
    const int wr   = wv >> 2;        // 0..1: wave row-half (128 rows)
    const int wc   = wv & 3;         // 0..3: wave col-quarter (64 cols)

    int nwg = gridDim.x, bid = blockIdx.x, w;
    if ((nwg & 7) == 0) w = (bid & 7) * (nwg >> 3) + (bid >> 3);
    else                w = bid;
    const int brow = (w >> 2) * 256;
    const int bn   = (w & 3) * 256;

    f32x4 acc[8][4];
#pragma unroll
    for (int f = 0; f < 8; ++f)
#pragma unroll
        for (int j = 0; j < 4; ++j) acc[f][j] = (f32x4){0.f, 0.f, 0.f, 0.f};

    const unsigned short* Ab = Abf + (size_t)brow * KPAD;
    const unsigned short* Bb = Bcat + (size_t)bn * KCAT;

    auto stageHalf = [&](const unsigned short* gbase, int rstride, int kcol,
                         int h, unsigned short* tile) {
        int c   = h * 512 + wv * 64 + lane;
        int row = c >> 2;
        int lk  = ((c & 3) ^ ((row >> 1) & 3)) * 8;
        const unsigned short* src = gbase + (size_t)row * rstride + kcol + lk;
        __builtin_amdgcn_global_load_lds(
            (const __attribute__((address_space(1))) void*)src,
            (__attribute__((address_space(3))) void*)(tile + (size_t)(h * 512 + wv * 64) * 8),
            16, 0, 0);
    };

    const int frow = lane & 15;
    const int fsl  = (((lane >> 4) & 3) ^ ((frow >> 1) & 3)) * 8;

    bf16x8 a[4], b0[4], b1[4], b2[4];
    auto loadA = [&](const unsigned short* Ac, int mh) {
#pragma unroll
        for (int i = 0; i < 4; ++i)
            a[i] = *(const bf16x8*)&Ac[(wr * 128 + mh * 64 + i * 16 + frow) * 32 + fsl];
    };
    auto loadB = [&](const unsigned short* Bc, bf16x8* b) {
#pragma unroll
        for (int j = 0; j < 4; ++j)
            b[j] = *(const bf16x8*)&Bc[(wc * 64 + j * 16 + frow) * 32 + fsl];
    };
    auto mm = [&](int mh, const bf16x8* b) {
        __builtin_amdgcn_s_setprio(1);
#pragma unroll
        for (int j = 0; j < 4; ++j)
#pragma unroll
            for (int i = 0; i < 4; ++i)
                acc[mh * 4 + i][j] = __builtin_amdgcn_mfma_f32_16x16x32_bf16(
                    a[i], b[j], acc[mh * 4 + i][j], 0, 0, 0);
        __builtin_amdgcn_s_setprio(0);
    };

    // prologue: stage K-tile 0 into buf0 (8 halves), full drain, barrier.
    stageHalf(Ab, KPAD, 0, 0, As[0]);
    stageHalf(Ab, KPAD, 0, 1, As[0]);
#pragma unroll
    for (int s = 0; s < 3; ++s) {
        stageHalf(Bb, KCAT, s * KPAD, 0, Bs[0][s]);
        stageHalf(Bb, KCAT, s * KPAD, 1, Bs[0][s]);
    }
    asm volatile("s_waitcnt vmcnt(0)" ::: "memory");
    __builtin_amdgcn_s_barrier();

    for (int kt = 0; kt < KT_N; ++kt) {
        const int buf = kt & 1;
        const unsigned short* Ac = As[buf];
        const unsigned short* B0 = Bs[buf][0];
        const unsigned short* B1 = Bs[buf][1];
        const unsigned short* B2 = Bs[buf][2];
        const bool st = (kt + 1 < KT_N);
        const int kc = (kt + 1) * 32;

        // ph1: wait A,B0(cur); stage A(nxt); BAR; ds a0,b0; mm; BAR
        asm volatile("s_waitcnt vmcnt(4)" ::: "memory");
        if (st) { stageHalf(Ab, KPAD, kc, 0, As[buf ^ 1]);
                  stageHalf(Ab, KPAD, kc, 1, As[buf ^ 1]); }
        __builtin_amdgcn_s_barrier();
        loadA(Ac, 0);
        loadB(B0, b0);
        mm(0, b0);
        __builtin_amdgcn_s_barrier();
        // ph2: wait B1(cur); stage B0(nxt); BAR; ds b1; mm; BAR
        if (st) asm volatile("s_waitcnt vmcnt(4)" ::: "memory");
        else    asm volatile("s_waitcnt vmcnt(2)" ::: "memory");
        if (st) { stageHalf(Bb, KCAT, kc, 0, Bs[buf ^ 1][0]);
                  stageHalf(Bb, KCAT, kc, 1, Bs[buf ^ 1][0]); }
        __builtin_amdgcn_s_barrier();
        loadB(B1, b1);
        mm(0, b1);
        __builtin_amdgcn_s_barrier();
        // ph3: wait B2(cur); stage B1(nxt); BAR; ds b2; mm; BAR
        if (st) asm volatile("s_waitcnt vmcnt(4)" ::: "memory");
        else    asm volatile("s_waitcnt vmcnt(0)" ::: "memory");
        if (st) { stageHalf(Bb, KCAT, KPAD + kc, 0, Bs[buf ^ 1][1]);
                  stageHalf(Bb, KCAT, KPAD + kc, 1, Bs[buf ^ 1][1]); }
        __builtin_amdgcn_s_barrier();
        loadB(B2, b2);
        mm(0, b2);
        __builtin_amdgcn_s_barrier();
        // ph4: stage B2(nxt); ds a1 (covered by ph1 wait) pre-barrier; mm; BAR
        if (st) { stageHalf(Bb, KCAT, 2 * KPAD + kc, 0, Bs[buf ^ 1][2]);
                  stageHalf(Bb, KCAT, 2 * KPAD + kc, 1, Bs[buf ^ 1][2]); }
        loadA(Ac, 1);
        __builtin_amdgcn_s_barrier();
        mm(1, b0);
        __builtin_amdgcn_s_barrier();
        // ph5
        mm(1, b1);
        __builtin_amdgcn_s_barrier();
        // ph6 (no drain — ladder handles it next iter)
        mm(1, b2);
        __builtin_amdgcn_s_barrier();
    }

    // C/D layout: col = lane&15, row = (lane>>4)*4 + q; acc[f] rows = f*16.
#pragma unroll
    for (int f = 0; f < 8; ++f) {
#pragma unroll
        for (int j = 0; j < 4; ++j) {
            int col  = bn + wc * 64 + j * 16 + (lane & 15);
            int row0 = brow + wr * 128 + f * 16 + ((lane >> 4) << 2);
#pragma unroll
            for (int q = 0; q < 4; ++q)
                C[(size_t)(row0 + q) * NH + col] = acc[f][j][q];
        }
    }
}

// ---------------------------------------------------------------------------
// K3: LIF scan, 2 h per thread (float2 loads), 4-deep prefetch,
//   j-interleaved spike words (R12-proven). Bit-identical LIF arithmetic.
// ---------------------------------------------------------------------------
__global__ __launch_bounds__(256) void k3_lif(const float* __restrict__ cur1,
                                              float* __restrict__ mem1,
                                              unsigned long long* __restrict__ bits,
                                              int TC) {
    const int b    = blockIdx.x >> 1;
    const int half = blockIdx.x & 1;
    const int wv   = threadIdx.x >> 6;
    const int lane = threadIdx.x & 63;
    const int h    = half * 512 + wv * 128 + lane * 2;
    const size_t S = (size_t)BATCH * NH;
    const float* p = cur1 + (size_t)b * NH + h;
    unsigned long long* bp = bits + (size_t)b * 16 + (half * 4 + wv) * 2;
    const bool lead = lane == 0;

    float2 mm = *(const float2*)(mem1 + b * NH + h);
    float m0 = mm.x, m1 = mm.y;

    auto ld = [&](int t) -> float2 {
        int tt = t < TC ? t : TC - 1;
        return *(const float2*)(p + (size_t)tt * S);
    };

#define K3_STEP(cv, t)                                                         \
    {                                                                          \
        float r0 = (m0 > 1.f) ? 1.f : 0.f;                                     \
        m0 = fmaf(BETAF, m0, (cv).x) - r0;                                     \
        float r1 = (m1 > 1.f) ? 1.f : 0.f;                                     \
        m1 = fmaf(BETAF, m1, (cv).y) - r1;                                     \
        unsigned long long w0 = __ballot(m0 > 1.f);                            \
        unsigned long long w1 = __ballot(m1 > 1.f);                            \
        if (lead) {                                                            \
            ulonglong2 v; v.x = w0; v.y = w1;                                  \
            *(ulonglong2*)(bp + (size_t)(t) * (BATCH * 16)) = v;               \
        }                                                                      \
    }

    float2 c0 = ld(0), c1 = ld(1), c2 = ld(2), c3 = ld(3);
    int tc = 0;
    for (; tc + 4 <= TC; tc += 4) {
        K3_STEP(c0, tc + 0); c0 = ld(tc + 4);
        K3_STEP(c1, tc + 1); c1 = ld(tc + 5);
        K3_STEP(c2, tc + 2); c2 = ld(tc + 6);
        K3_STEP(c3, tc + 3); c3 = ld(tc + 7);
    }
    for (; tc < TC; ++tc) { float2 c = ld(tc); K3_STEP(c, tc); }
#undef K3_STEP
    float2 mo; mo.x = m0; mo.y = m1;
    *(float2*)(mem1 + b * NH + h) = mo;
}

// ---------------------------------------------------------------------------
// K4: fc2 sparse gather, one wave per (t,b) row, 4 rows/block.
//   Word i maps h = (i>>1)*128 + 2*bit + (i&1).
// ---------------------------------------------------------------------------
__global__ __launch_bounds__(256) void k4_fc2(const unsigned long long* __restrict__ bits,
                                              const float* __restrict__ W2T,
                                              float* __restrict__ cur2) {
    int row  = blockIdx.x * 4 + (threadIdx.x >> 6);
    int lane = threadIdx.x & 63;
    bool act = lane < NO;
    unsigned long long mv = (lane < 16) ? bits[(size_t)row * 16 + lane] : 0ULL;
    const float* W = W2T + (act ? lane : 0);
    float p0 = 0.f, p1 = 0.f;
#pragma unroll
    for (int i = 0; i < 16; ++i) {
        unsigned long long m = __shfl(mv, i);
        int base = (i >> 1) * 128 + (i & 1);
        while (m) {
            int  b0 = __ffsll(m) - 1;            m &= m - 1;
            bool v1 = m != 0;
            int  b1 = v1 ? __ffsll(m) - 1 : 0;   m &= m - 1;
            float w0 = W[(base + 2 * b0) * NO];
            float w1 = W[(base + 2 * b1) * NO];
            p0 += w0;
            p1 += v1 ? w1 : 0.f;
        }
    }
    if (act) cur2[(size_t)row * NO + lane] = p0 + p1;
}

// ---------------------------------------------------------------------------
// K5: leaky readout + softmax; 128 blocks x 64 threads.
// ---------------------------------------------------------------------------
__global__ __launch_bounds__(64) void k5_readout(const float* __restrict__ cur2,
                                                 float* __restrict__ out_mem,
                                                 float* __restrict__ out_sm) {
    int b = blockIdx.x * 2 + (threadIdx.x >> 5);
    int o = threadIdx.x & 31;
    bool act = o < NO;
    const float* p = cur2 + (size_t)b * NO + (act ? o : 0);
    float mem = 0.f;
    float nxt = p[0];
    for (int t = 0; t < T_STEPS; ++t) {
        float c = nxt;
        if (t + 1 < T_STEPS) nxt = p[(size_t)(t + 1) * BATCH * NO];
        mem = fmaf(BETAF, mem, c);
        float e = act ? __expf(mem) : 0.f;
        float s = e;
#pragma unroll
        for (int off = 16; off; off >>= 1) s += __shfl_xor(s, off, 32);
        if (act) {
            int base = (t * BATCH + b) * NO;
            out_mem[base + o] = mem;
            out_sm[base + o] = __fdividef(e, s);
        }
    }
}

// ---------------------------------------------------------------------------
extern "C" void kernel_launch(void* const* d_in, const int* in_sizes, int n_in,
                              void* d_out, int out_size, void* d_ws, size_t ws_size,
                              hipStream_t stream) {
    const float* spikes = (const float*)d_in[0];   // [250,256,700]
    const float* W1     = (const float*)d_in[1];   // [1024,700]
    const float* W2     = (const float*)d_in[2];   // [20,1024]
    float* out_mem = (float*)d_out;                              // [250,256,20]
    float* out_sm  = out_mem + (size_t)T_STEPS * BATCH * NO;     // [250,256,20]

    char* ws = (char*)d_ws;
    size_t off = 0;
    auto alloc = [&](size_t bytes) -> char* {
        off = (off + 255) & ~(size_t)255;
        char* p = ws + off;
        off += bytes;
        return p;
    };
    float*          W2T  = (float*)alloc((size_t)NH * NO * 4);
    float*          mem1 = (float*)alloc((size_t)BATCH * NH * 4);
    float*          cur2 = (float*)alloc((size_t)T_STEPS * BATCH * NO * 4);
    unsigned short* Bcat = (unsigned short*)alloc((size_t)NH * KCAT * 2);

    // T-chunking: per step need cur1 (1 MB) + Abf (352 KB) + bits (32 KB).
    size_t fixed = (off + 255) & ~(size_t)255;
    size_t rem = ws_size > fixed ? ws_size - fixed : 0;
    size_t per_t = (size_t)BATCH * NH * 4 + (size_t)BATCH * KPAD * 2
                 + (size_t)BATCH * 16 * 8 + 768;
    int TC = (int)(rem / per_t);
    if (TC > T_STEPS) TC = T_STEPS;
    if (TC < 1) TC = 1;
    float*              cur1 = (float*)alloc((size_t)TC * BATCH * NH * 4);
    unsigned short*     Abf  = (unsigned short*)alloc((size_t)TC * BATCH * KPAD * 2);
    unsigned long long* bits = (unsigned long long*)alloc((size_t)TC * BATCH * 16 * 8);

    k0_init<<<(NH * KPAD + 255) / 256, 256, 0, stream>>>(W1, W2, W2T, mem1, Bcat);

    for (int t0 = 0; t0 < T_STEPS; t0 += TC) {
        int tc = T_STEPS - t0 < TC ? T_STEPS - t0 : TC;
        int rows = tc * BATCH;
        k1_cvt<<<(rows * 176 + 255) / 256, 256, 0, stream>>>(
            spikes + (size_t)t0 * BATCH * NI, Abf, rows);
        int nwg = (rows / 256) * 4;   // 256-row m-tiles x 4 n-tiles
        k2_fc1<<<nwg, 512, 0, stream>>>(Abf, Bcat, cur1);
        k3_lif<<<512, 256, 0, stream>>>(cur1, mem1, bits, tc);
        k4_fc2<<<rows / 4, 256, 0, stream>>>(bits, W2T, cur2 + (size_t)t0 * BATCH * NO);
    }

    k5_readout<<<128, 64, 0, stream>>>(cur2, out_mem, out_sm);
}

// Round 15
// 509.608 us; speedup vs baseline: 1.6850x; 1.0162x over previous
//
#include <hip/hip_runtime.h>
#include <hip/hip_bf16.h>
#include <cstdint>

#define T_STEPS 250
#define BATCH   256
#define NI      700
#define NH      1024
#define NO      20
#define BETAF   0.9f
#define KPAD    704          // 22 * 32
#define KT_N    22
#define KCAT    2112         // 3 * KPAD

typedef __attribute__((ext_vector_type(8))) short bf16x8;
typedef __attribute__((ext_vector_type(4))) float f32x4;

static __device__ __forceinline__ unsigned short f2bu(float x) {
    union { __hip_bfloat16 h; unsigned short u; } c;
    c.h = __float2bfloat16(x);
    return c.u;
}
static __device__ __forceinline__ float b2f(unsigned short u) {
    union { __hip_bfloat16 h; unsigned short u; } c;
    c.u = u;
    return __bfloat162float(c.h);
}

// ---------------------------------------------------------------------------
// K0: zero LIF state; W2T[h][o]; Bcat = [hi|mid|lo] bf16 split of W1,
//     padded K 700->704. LOCKED (only decomposition with pass evidence).
// ---------------------------------------------------------------------------
__global__ __launch_bounds__(256) void k0_init(const float* __restrict__ W1,
                                               const float* __restrict__ W2,
                                               float* __restrict__ W2T,
                                               float* __restrict__ mem1,
                                               unsigned short* __restrict__ Bcat) {
    int idx = blockIdx.x * 256 + threadIdx.x;
    if (idx < BATCH * NH) mem1[idx] = 0.f;
    if (idx < NH * NO) {
        int h = idx / NO, o = idx % NO;
        W2T[idx] = W2[o * NH + h];
    }
    if (idx < NH * KPAD) {
        int n = idx / KPAD, k = idx % KPAD;
        float w = (k < NI) ? W1[n * NI + k] : 0.f;
        unsigned short hu = f2bu(w);
        float r1 = w - b2f(hu);
        unsigned short mu = f2bu(r1);
        float r2 = r1 - b2f(mu);
        unsigned short lu = f2bu(r2);
        unsigned short* row = Bcat + (size_t)n * KCAT + k;
        row[0]        = hu;
        row[KPAD]     = mu;
        row[2 * KPAD] = lu;
    }
}

// ---------------------------------------------------------------------------
// K1: convert fp32 binary spikes [rows][700] -> bf16 [rows][704] (exact).
// ---------------------------------------------------------------------------
__global__ __launch_bounds__(256) void k1_cvt(const float* __restrict__ A,
                                              unsigned short* __restrict__ Abf,
                                              int rows) {
    int idx = blockIdx.x * 256 + threadIdx.x;   // quad index: 176 per row
    int r = idx / 176, q = idx - r * 176;
    if (r >= rows) return;
    int k = q * 4;
    ushort4 o = make_ushort4(0, 0, 0, 0);
    if (k < NI) {
        float4 v = *(const float4*)(A + (size_t)r * NI + k);
        o.x = f2bu(v.x); o.y = f2bu(v.y); o.z = f2bu(v.z); o.w = f2bu(v.w);
    }
    *(ushort4*)(Abf + (size_t)r * KPAD + k) = o;
}

// ---------------------------------------------------------------------------
// K2 v4: 256x128 tile / BK=32 / 8 waves / 3 phases / 80KB LDS -> 2 blocks/CU
//   (16 waves/CU: restores the cross-block overlap that made R4 win, ON TOP
//   of the R13/R14-proven counted-vmcnt phase schedule).
//   Wave (wr=wv>>1, wc=wv&1) owns 64x64 out; 16 MFMA/phase, 3 splits/iter.
//   Per-wave stages/iter (FIFO): A×2@ph1, B0@ph2, B1,B2@ph3. Waits:
//     ph1 vmcnt(2) forces A,B0(cur) | ph2 vmcnt(3) forces B1(cur)
//     ph3 vmcnt(3) forces B2(cur)   | epilogue 2/1/0. No vmcnt(0) in loop;
//   every load has >=3 phases of cover. Race-free as R13/R14 (stage into
//   buf^1 only after the barrier that ends that buffer's last reader phase).
//   BIT-IDENTICAL cur1 (kt asc, s asc, same 16x16x32 ops). R4-proven 64B-row
//   swizzle (0 conflicts), rule-21 staging, XCD-grouped bid swizzle.
//   One b[4] live at a time: acc 64 + a 16 + b 16 VGPR -> fits 128/wave.
// ---------------------------------------------------------------------------
__global__ __launch_bounds__(512, 4) void k2_fc1(const unsigned short* __restrict__ Abf,
                                                 const unsigned short* __restrict__ Bcat,
                                                 float* __restrict__ C) {
    __shared__ unsigned short As[2][256 * 32];      // 2 x 16 KB
    __shared__ unsigned short Bs[2][3][128 * 32];   // 2 x 3 x 8 KB
    const int tid  = threadIdx.x;
    const int lane = tid & 63;
    const int wv   = tid >> 6;
    const int wr   = wv >> 1;        // 0..3: wave row-quarter (64 rows)
    const int wc   = wv & 1;         // 0..1: wave col-half (64 cols)

    int nwg = gridDim.x, bid = blockIdx.x, w;
    if ((nwg & 7) == 0) w = (bid & 7) * (nwg >> 3) + (bid >> 3);
    else                w = bid;
    const int brow = (w >> 3) * 256;
    const int bn   = (w & 7) * 128;

    f32x4 acc[4][4];
#pragma unroll
    for (int i = 0; i < 4; ++i)
#pragma unroll
        for (int j = 0; j < 4; ++j) acc[i][j] = (f32x4){0.f, 0.f, 0.f, 0.f};

    const unsigned short* Ab = Abf + (size_t)brow * KPAD;
    const unsigned short* Bb = Bcat + (size_t)bn * KCAT;

    // A tile: 256x32 = 1024 16B chunks, 2 gload_lds/thread.
    auto stageA = [&](int kcol, unsigned short* tile) {
#pragma unroll
        for (int j = 0; j < 2; ++j) {
            int c   = j * 512 + wv * 64 + lane;
            int row = c >> 2;
            int lk  = ((c & 3) ^ ((row >> 1) & 3)) * 8;
            const unsigned short* src = Ab + (size_t)row * KPAD + kcol + lk;
            __builtin_amdgcn_global_load_lds(
                (const __attribute__((address_space(1))) void*)src,
                (__attribute__((address_space(3))) void*)(tile + (size_t)(j * 512 + wv * 64) * 8),
                16, 0, 0);
        }
    };
    // B split tile: 128x32 = 512 chunks, 1 gload_lds/thread.
    auto stageB = [&](int kcol, unsigned short* tile) {
        int c   = wv * 64 + lane;
        int row = c >> 2;
        int lk  = ((c & 3) ^ ((row >> 1) & 3)) * 8;
        const unsigned short* src = Bb + (size_t)row * KCAT + kcol + lk;
        __builtin_amdgcn_global_load_lds(
            (const __attribute__((address_space(1))) void*)src,
            (__attribute__((address_space(3))) void*)(tile + (size_t)(wv * 64) * 8),
            16, 0, 0);
    };

    const int frow = lane & 15;
    const int fsl  = (((lane >> 4) & 3) ^ ((frow >> 1) & 3)) * 8;

    bf16x8 a[4], b[4];
    auto loadA = [&](const unsigned short* Ac) {
#pragma unroll
        for (int i = 0; i < 4; ++i)
            a[i] = *(const bf16x8*)&Ac[(wr * 64 + i * 16 + frow) * 32 + fsl];
    };
    auto loadB = [&](const unsigned short* Bc) {
#pragma unroll
        for (int j = 0; j < 4; ++j)
            b[j] = *(const bf16x8*)&Bc[(wc * 64 + j * 16 + frow) * 32 + fsl];
    };
    auto mm = [&]() {
        __builtin_amdgcn_s_setprio(1);
#pragma unroll
        for (int j = 0; j < 4; ++j)
#pragma unroll
            for (int i = 0; i < 4; ++i)
                acc[i][j] = __builtin_amdgcn_mfma_f32_16x16x32_bf16(
                    a[i], b[j], acc[i][j], 0, 0, 0);
        __builtin_amdgcn_s_setprio(0);
    };

    // prologue: stage K-tile 0 (A + 3 B-splits), full drain, barrier.
    stageA(0, As[0]);
#pragma unroll
    for (int s = 0; s < 3; ++s) stageB(s * KPAD, Bs[0][s]);
    asm volatile("s_waitcnt vmcnt(0)" ::: "memory");
    __builtin_amdgcn_s_barrier();

    for (int kt = 0; kt < KT_N; ++kt) {
        const int buf = kt & 1;
        const bool st = (kt + 1 < KT_N);
        const int kc = (kt + 1) * 32;

        // ph1: wait A,B0(cur); stage A(nxt); BAR; ds a,b0; mm; BAR
        asm volatile("s_waitcnt vmcnt(2)" ::: "memory");
        if (st) stageA(kc, As[buf ^ 1]);
        __builtin_amdgcn_s_barrier();
        loadA(As[buf]);
        loadB(Bs[buf][0]);
        mm();
        __builtin_amdgcn_s_barrier();
        // ph2: wait B1(cur); stage B0(nxt); BAR; ds b1; mm; BAR
        if (st) asm volatile("s_waitcnt vmcnt(3)" ::: "memory");
        else    asm volatile("s_waitcnt vmcnt(1)" ::: "memory");
        if (st) stageB(kc, Bs[buf ^ 1][0]);
        __builtin_amdgcn_s_barrier();
        loadB(Bs[buf][1]);
        mm();
        __builtin_amdgcn_s_barrier();
        // ph3: wait B2(cur); stage B1,B2(nxt); BAR; ds b2; mm; BAR
        if (st) asm volatile("s_waitcnt vmcnt(3)" ::: "memory");
        else    asm volatile("s_waitcnt vmcnt(0)" ::: "memory");
        if (st) { stageB(KPAD + kc, Bs[buf ^ 1][1]);
                  stageB(2 * KPAD + kc, Bs[buf ^ 1][2]); }
        __builtin_amdgcn_s_barrier();
        loadB(Bs[buf][2]);
        mm();
        __builtin_amdgcn_s_barrier();
    }

    // C/D layout: col = lane&15, row = (lane>>4)*4 + q.
#pragma unroll
    for (int i = 0; i < 4; ++i) {
#pragma unroll
        for (int j = 0; j < 4; ++j) {
            int col  = bn + wc * 64 + j * 16 + (lane & 15);
            int row0 = brow + wr * 64 + i * 16 + ((lane >> 4) << 2);
#pragma unroll
            for (int q = 0; q < 4; ++q)
                C[(size_t)(row0 + q) * NH + col] = acc[i][j][q];
        }
    }
}

// ---------------------------------------------------------------------------
// K3: LIF scan, 2 h per thread (float2 loads), 4-deep prefetch,
//   j-interleaved spike words (R12-proven). Bit-identical LIF arithmetic.
// ---------------------------------------------------------------------------
__global__ __launch_bounds__(256) void k3_lif(const float* __restrict__ cur1,
                                              float* __restrict__ mem1,
                                              unsigned long long* __restrict__ bits,
                                              int TC) {
    const int b    = blockIdx.x >> 1;
    const int half = blockIdx.x & 1;
    const int wv   = threadIdx.x >> 6;
    const int lane = threadIdx.x & 63;
    const int h    = half * 512 + wv * 128 + lane * 2;
    const size_t S = (size_t)BATCH * NH;
    const float* p = cur1 + (size_t)b * NH + h;
    unsigned long long* bp = bits + (size_t)b * 16 + (half * 4 + wv) * 2;
    const bool lead = lane == 0;

    float2 mm = *(const float2*)(mem1 + b * NH + h);
    float m0 = mm.x, m1 = mm.y;

    auto ld = [&](int t) -> float2 {
        int tt = t < TC ? t : TC - 1;
        return *(const float2*)(p + (size_t)tt * S);
    };

#define K3_STEP(cv, t)                                                         \
    {                                                                          \
        float r0 = (m0 > 1.f) ? 1.f : 0.f;                                     \
        m0 = fmaf(BETAF, m0, (cv).x) - r0;                                     \
        float r1 = (m1 > 1.f) ? 1.f : 0.f;                                     \
        m1 = fmaf(BETAF, m1, (cv).y) - r1;                                     \
        unsigned long long w0 = __ballot(m0 > 1.f);                            \
        unsigned long long w1 = __ballot(m1 > 1.f);                            \
        if (lead) {                                                            \
            ulonglong2 v; v.x = w0; v.y = w1;                                  \
            *(ulonglong2*)(bp + (size_t)(t) * (BATCH * 16)) = v;               \
        }                                                                      \
    }

    float2 c0 = ld(0), c1 = ld(1), c2 = ld(2), c3 = ld(3);
    int tc = 0;
    for (; tc + 4 <= TC; tc += 4) {
        K3_STEP(c0, tc + 0); c0 = ld(tc + 4);
        K3_STEP(c1, tc + 1); c1 = ld(tc + 5);
        K3_STEP(c2, tc + 2); c2 = ld(tc + 6);
        K3_STEP(c3, tc + 3); c3 = ld(tc + 7);
    }
    for (; tc < TC; ++tc) { float2 c = ld(tc); K3_STEP(c, tc); }
#undef K3_STEP
    float2 mo; mo.x = m0; mo.y = m1;
    *(float2*)(mem1 + b * NH + h) = mo;
}

// ---------------------------------------------------------------------------
// K4: fc2 sparse gather, one wave per (t,b) row, 4 rows/block.
//   Word i maps h = (i>>1)*128 + 2*bit + (i&1).
// ---------------------------------------------------------------------------
__global__ __launch_bounds__(256) void k4_fc2(const unsigned long long* __restrict__ bits,
                                              const float* __restrict__ W2T,
                                              float* __restrict__ cur2) {
    int row  = blockIdx.x * 4 + (threadIdx.x >> 6);
    int lane = threadIdx.x & 63;
    bool act = lane < NO;
    unsigned long long mv = (lane < 16) ? bits[(size_t)row * 16 + lane] : 0ULL;
    const float* W = W2T + (act ? lane : 0);
    float p0 = 0.f, p1 = 0.f;
#pragma unroll
    for (int i = 0; i < 16; ++i) {
        unsigned long long m = __shfl(mv, i);
        int base = (i >> 1) * 128 + (i & 1);
        while (m) {
            int  b0 = __ffsll(m) - 1;            m &= m - 1;
            bool v1 = m != 0;
            int  b1 = v1 ? __ffsll(m) - 1 : 0;   m &= m - 1;
            float w0 = W[(base + 2 * b0) * NO];
            float w1 = W[(base + 2 * b1) * NO];
            p0 += w0;
            p1 += v1 ? w1 : 0.f;
        }
    }
    if (act) cur2[(size_t)row * NO + lane] = p0 + p1;
}

// ---------------------------------------------------------------------------
// K5: leaky readout + softmax; 128 blocks x 64 threads.
// ---------------------------------------------------------------------------
__global__ __launch_bounds__(64) void k5_readout(const float* __restrict__ cur2,
                                                 float* __restrict__ out_mem,
                                                 float* __restrict__ out_sm) {
    int b = blockIdx.x * 2 + (threadIdx.x >> 5);
    int o = threadIdx.x & 31;
    bool act = o < NO;
    const float* p = cur2 + (size_t)b * NO + (act ? o : 0);
    float mem = 0.f;
    float nxt = p[0];
    for (int t = 0; t < T_STEPS; ++t) {
        float c = nxt;
        if (t + 1 < T_STEPS) nxt = p[(size_t)(t + 1) * BATCH * NO];
        mem = fmaf(BETAF, mem, c);
        float e = act ? __expf(mem) : 0.f;
        float s = e;
#pragma unroll
        for (int off = 16; off; off >>= 1) s += __shfl_xor(s, off, 32);
        if (act) {
            int base = (t * BATCH + b) * NO;
            out_mem[base + o] = mem;
            out_sm[base + o] = __fdividef(e, s);
        }
    }
}

// ---------------------------------------------------------------------------
extern "C" void kernel_launch(void* const* d_in, const int* in_sizes, int n_in,
                              void* d_out, int out_size, void* d_ws, size_t ws_size,
                              hipStream_t stream) {
    const float* spikes = (const float*)d_in[0];   // [250,256,700]
    const float* W1     = (const float*)d_in[1];   // [1024,700]
    const float* W2     = (const float*)d_in[2];   // [20,1024]
    float* out_mem = (float*)d_out;                              // [250,256,20]
    float* out_sm  = out_mem + (size_t)T_STEPS * BATCH * NO;     // [250,256,20]

    char* ws = (char*)d_ws;
    size_t off = 0;
    auto alloc = [&](size_t bytes) -> char* {
        off = (off + 255) & ~(size_t)255;
        char* p = ws + off;
        off += bytes;
        return p;
    };
    float*          W2T  = (float*)alloc((size_t)NH * NO * 4);
    float*          mem1 = (float*)alloc((size_t)BATCH * NH * 4);
    float*          cur2 = (float*)alloc((size_t)T_STEPS * BATCH * NO * 4);
    unsigned short* Bcat = (unsigned short*)alloc((size_t)NH * KCAT * 2);

    // T-chunking: per step need cur1 (1 MB) + Abf (352 KB) + bits (32 KB).
    size_t fixed = (off + 255) & ~(size_t)255;
    size_t rem = ws_size > fixed ? ws_size - fixed : 0;
    size_t per_t = (size_t)BATCH * NH * 4 + (size_t)BATCH * KPAD * 2
                 + (size_t)BATCH * 16 * 8 + 768;
    int TC = (int)(rem / per_t);
    if (TC > T_STEPS) TC = T_STEPS;
    if (TC < 1) TC = 1;
    float*              cur1 = (float*)alloc((size_t)TC * BATCH * NH * 4);
    unsigned short*     Abf  = (unsigned short*)alloc((size_t)TC * BATCH * KPAD * 2);
    unsigned long long* bits = (unsigned long long*)alloc((size_t)TC * BATCH * 16 * 8);

    k0_init<<<(NH * KPAD + 255) / 256, 256, 0, stream>>>(W1, W2, W2T, mem1, Bcat);

    for (int t0 = 0; t0 < T_STEPS; t0 += TC) {
        int tc = T_STEPS - t0 < TC ? T_STEPS - t0 : TC;
        int rows = tc * BATCH;
        k1_cvt<<<(rows * 176 + 255) / 256, 256, 0, stream>>>(
            spikes + (size_t)t0 * BATCH * NI, Abf, rows);
        int nwg = (rows / 256) * 8;   // 256-row m-tiles x 8 n-tiles (128 cols)
        k2_fc1<<<nwg, 512, 0, stream>>>(Abf, Bcat, cur1);
        k3_lif<<<512, 256, 0, stream>>>(cur1, mem1, bits, tc);
        k4_fc2<<<rows / 4, 256, 0, stream>>>(bits, W2T, cur2 + (size_t)t0 * BATCH * NO);
    }

    k5_readout<<<128, 64, 0, stream>>>(cur2, out_mem, out_sm);
}

// Round 16
// 504.120 us; speedup vs baseline: 1.7033x; 1.0109x over previous
//
#include <hip/hip_runtime.h>
#include <hip/hip_bf16.h>
#include <cstdint>

#define T_STEPS 250
#define BATCH   256
#define NI      700
#define NH      1024
#define NO      20
#define BETAF   0.9f
#define KPAD    704          // 22 * 32
#define KT_N    22
#define KCAT    2112         // 3 * KPAD

typedef __attribute__((ext_vector_type(8))) short bf16x8;
typedef __attribute__((ext_vector_type(4))) float f32x4;

static __device__ __forceinline__ unsigned short f2bu(float x) {
    union { __hip_bfloat16 h; unsigned short u; } c;
    c.h = __float2bfloat16(x);
    return c.u;
}
static __device__ __forceinline__ float b2f(unsigned short u) {
    union { __hip_bfloat16 h; unsigned short u; } c;
    c.u = u;
    return __bfloat162float(c.h);
}

// ---------------------------------------------------------------------------
// K0: zero LIF state; W2T[h][o]; Bcat = [hi|mid|lo] bf16 split of W1,
//     padded K 700->704. LOCKED (only decomposition with pass evidence).
// ---------------------------------------------------------------------------
__global__ __launch_bounds__(256) void k0_init(const float* __restrict__ W1,
                                               const float* __restrict__ W2,
                                               float* __restrict__ W2T,
                                               float* __restrict__ mem1,
                                               unsigned short* __restrict__ Bcat) {
    int idx = blockIdx.x * 256 + threadIdx.x;
    if (idx < BATCH * NH) mem1[idx] = 0.f;
    if (idx < NH * NO) {
        int h = idx / NO, o = idx % NO;
        W2T[idx] = W2[o * NH + h];
    }
    if (idx < NH * KPAD) {
        int n = idx / KPAD, k = idx % KPAD;
        float w = (k < NI) ? W1[n * NI + k] : 0.f;
        unsigned short hu = f2bu(w);
        float r1 = w - b2f(hu);
        unsigned short mu = f2bu(r1);
        float r2 = r1 - b2f(mu);
        unsigned short lu = f2bu(r2);
        unsigned short* row = Bcat + (size_t)n * KCAT + k;
        row[0]        = hu;
        row[KPAD]     = mu;
        row[2 * KPAD] = lu;
    }
}

// ---------------------------------------------------------------------------
// K1: convert fp32 binary spikes [rows][700] -> bf16 [rows][704] (exact).
// ---------------------------------------------------------------------------
__global__ __launch_bounds__(256) void k1_cvt(const float* __restrict__ A,
                                              unsigned short* __restrict__ Abf,
                                              int rows) {
    int idx = blockIdx.x * 256 + threadIdx.x;   // quad index: 176 per row
    int r = idx / 176, q = idx - r * 176;
    if (r >= rows) return;
    int k = q * 4;
    ushort4 o = make_ushort4(0, 0, 0, 0);
    if (k < NI) {
        float4 v = *(const float4*)(A + (size_t)r * NI + k);
        o.x = f2bu(v.x); o.y = f2bu(v.y); o.z = f2bu(v.z); o.w = f2bu(v.w);
    }
    *(ushort4*)(Abf + (size_t)r * KPAD + k) = o;
}

// ---------------------------------------------------------------------------
// K2 v5: 256x128 tile / BK=32 / 8 waves / 80KB LDS / 2 blocks/CU — R15's
//   proven shape with the 3 phases MERGED into ONE heavy phase per K-iter:
//     wait vmcnt(5)      // forces the 5 cur-tile loads (staged last iter)
//     stage(kt+1): 5 gload_lds -> buf^1   (10 outstanding after issue)
//     BARRIER
//     loadA; b0->16 MFMA; b1->16 MFMA; b2->16 MFMA   (48-MFMA cluster)
//     BARRIER
//   Barriers 6->2/iter, waits 3->1; each staged load gets a full 48-MFMA
//   phase (~300cy) of cover. b's loaded sequentially (one b[4] live) so
//   VGPR stays <=~80 -> 4 waves/SIMD -> 2 blocks/CU preserved.
//   Race-free: stage into buf^1 issues after the end-of-prev-iter barrier
//   (all reads of buf^1 data-drained by prev MFMAs before it).
//   BIT-IDENTICAL cur1 (kt asc, s asc, same 16x16x32 ops). R4-proven
//   64B-row swizzle (0 conflicts), rule-21 staging, XCD-grouped bid swizzle.
// ---------------------------------------------------------------------------
__global__ __launch_bounds__(512, 4) void k2_fc1(const unsigned short* __restrict__ Abf,
                                                 const unsigned short* __restrict__ Bcat,
                                                 float* __restrict__ C) {
    __shared__ unsigned short As[2][256 * 32];      // 2 x 16 KB
    __shared__ unsigned short Bs[2][3][128 * 32];   // 2 x 3 x 8 KB
    const int tid  = threadIdx.x;
    const int lane = tid & 63;
    const int wv   = tid >> 6;
    const int wr   = wv >> 1;        // 0..3: wave row-quarter (64 rows)
    const int wc   = wv & 1;         // 0..1: wave col-half (64 cols)

    int nwg = gridDim.x, bid = blockIdx.x, w;
    if ((nwg & 7) == 0) w = (bid & 7) * (nwg >> 3) + (bid >> 3);
    else                w = bid;
    const int brow = (w >> 3) * 256;
    const int bn   = (w & 7) * 128;

    f32x4 acc[4][4];
#pragma unroll
    for (int i = 0; i < 4; ++i)
#pragma unroll
        for (int j = 0; j < 4; ++j) acc[i][j] = (f32x4){0.f, 0.f, 0.f, 0.f};

    const unsigned short* Ab = Abf + (size_t)brow * KPAD;
    const unsigned short* Bb = Bcat + (size_t)bn * KCAT;

    // A tile: 256x32 = 1024 16B chunks, 2 gload_lds/thread.
    auto stageA = [&](int kcol, unsigned short* tile) {
#pragma unroll
        for (int j = 0; j < 2; ++j) {
            int c   = j * 512 + wv * 64 + lane;
            int row = c >> 2;
            int lk  = ((c & 3) ^ ((row >> 1) & 3)) * 8;
            const unsigned short* src = Ab + (size_t)row * KPAD + kcol + lk;
            __builtin_amdgcn_global_load_lds(
                (const __attribute__((address_space(1))) void*)src,
                (__attribute__((address_space(3))) void*)(tile + (size_t)(j * 512 + wv * 64) * 8),
                16, 0, 0);
        }
    };
    // B split tile: 128x32 = 512 chunks, 1 gload_lds/thread.
    auto stageB = [&](int kcol, unsigned short* tile) {
        int c   = wv * 64 + lane;
        int row = c >> 2;
        int lk  = ((c & 3) ^ ((row >> 1) & 3)) * 8;
        const unsigned short* src = Bb + (size_t)row * KCAT + kcol + lk;
        __builtin_amdgcn_global_load_lds(
            (const __attribute__((address_space(1))) void*)src,
            (__attribute__((address_space(3))) void*)(tile + (size_t)(wv * 64) * 8),
            16, 0, 0);
    };

    const int frow = lane & 15;
    const int fsl  = (((lane >> 4) & 3) ^ ((frow >> 1) & 3)) * 8;

    bf16x8 a[4], b[4];
    auto loadA = [&](const unsigned short* Ac) {
#pragma unroll
        for (int i = 0; i < 4; ++i)
            a[i] = *(const bf16x8*)&Ac[(wr * 64 + i * 16 + frow) * 32 + fsl];
    };
    auto loadB = [&](const unsigned short* Bc) {
#pragma unroll
        for (int j = 0; j < 4; ++j)
            b[j] = *(const bf16x8*)&Bc[(wc * 64 + j * 16 + frow) * 32 + fsl];
    };
    auto mm = [&]() {
#pragma unroll
        for (int j = 0; j < 4; ++j)
#pragma unroll
            for (int i = 0; i < 4; ++i)
                acc[i][j] = __builtin_amdgcn_mfma_f32_16x16x32_bf16(
                    a[i], b[j], acc[i][j], 0, 0, 0);
    };

    // prologue: stage K-tile 0 (A + 3 B-splits), full drain, barrier.
    stageA(0, As[0]);
#pragma unroll
    for (int s = 0; s < 3; ++s) stageB(s * KPAD, Bs[0][s]);
    asm volatile("s_waitcnt vmcnt(0)" ::: "memory");
    __builtin_amdgcn_s_barrier();

    for (int kt = 0; kt < KT_N; ++kt) {
        const int buf = kt & 1;
        const bool st = (kt + 1 < KT_N);
        const int kc = (kt + 1) * 32;

        // single heavy phase per iter
        if (st) {
            asm volatile("s_waitcnt vmcnt(5)" ::: "memory");  // cur tile landed
            stageA(kc, As[buf ^ 1]);
            stageB(kc, Bs[buf ^ 1][0]);
            stageB(KPAD + kc, Bs[buf ^ 1][1]);
            stageB(2 * KPAD + kc, Bs[buf ^ 1][2]);
        } else {
            asm volatile("s_waitcnt vmcnt(0)" ::: "memory");  // last tile
        }
        __builtin_amdgcn_s_barrier();

        loadA(As[buf]);
        __builtin_amdgcn_s_setprio(1);
        loadB(Bs[buf][0]); mm();
        loadB(Bs[buf][1]); mm();
        loadB(Bs[buf][2]); mm();
        __builtin_amdgcn_s_setprio(0);
        __builtin_amdgcn_s_barrier();
    }

    // C/D layout: col = lane&15, row = (lane>>4)*4 + q.
#pragma unroll
    for (int i = 0; i < 4; ++i) {
#pragma unroll
        for (int j = 0; j < 4; ++j) {
            int col  = bn + wc * 64 + j * 16 + (lane & 15);
            int row0 = brow + wr * 64 + i * 16 + ((lane >> 4) << 2);
#pragma unroll
            for (int q = 0; q < 4; ++q)
                C[(size_t)(row0 + q) * NH + col] = acc[i][j][q];
        }
    }
}

// ---------------------------------------------------------------------------
// K3: LIF scan, 2 h per thread (float2 loads), 4-deep prefetch,
//   j-interleaved spike words (R12-proven). Bit-identical LIF arithmetic.
// ---------------------------------------------------------------------------
__global__ __launch_bounds__(256) void k3_lif(const float* __restrict__ cur1,
                                              float* __restrict__ mem1,
                                              unsigned long long* __restrict__ bits,
                                              int TC) {
    const int b    = blockIdx.x >> 1;
    const int half = blockIdx.x & 1;
    const int wv   = threadIdx.x >> 6;
    const int lane = threadIdx.x & 63;
    const int h    = half * 512 + wv * 128 + lane * 2;
    const size_t S = (size_t)BATCH * NH;
    const float* p = cur1 + (size_t)b * NH + h;
    unsigned long long* bp = bits + (size_t)b * 16 + (half * 4 + wv) * 2;
    const bool lead = lane == 0;

    float2 mm = *(const float2*)(mem1 + b * NH + h);
    float m0 = mm.x, m1 = mm.y;

    auto ld = [&](int t) -> float2 {
        int tt = t < TC ? t : TC - 1;
        return *(const float2*)(p + (size_t)tt * S);
    };

#define K3_STEP(cv, t)                                                         \
    {                                                                          \
        float r0 = (m0 > 1.f) ? 1.f : 0.f;                                     \
        m0 = fmaf(BETAF, m0, (cv).x) - r0;                                     \
        float r1 = (m1 > 1.f) ? 1.f : 0.f;                                     \
        m1 = fmaf(BETAF, m1, (cv).y) - r1;                                     \
        unsigned long long w0 = __ballot(m0 > 1.f);                            \
        unsigned long long w1 = __ballot(m1 > 1.f);                            \
        if (lead) {                                                            \
            ulonglong2 v; v.x = w0; v.y = w1;                                  \
            *(ulonglong2*)(bp + (size_t)(t) * (BATCH * 16)) = v;               \
        }                                                                      \
    }

    float2 c0 = ld(0), c1 = ld(1), c2 = ld(2), c3 = ld(3);
    int tc = 0;
    for (; tc + 4 <= TC; tc += 4) {
        K3_STEP(c0, tc + 0); c0 = ld(tc + 4);
        K3_STEP(c1, tc + 1); c1 = ld(tc + 5);
        K3_STEP(c2, tc + 2); c2 = ld(tc + 6);
        K3_STEP(c3, tc + 3); c3 = ld(tc + 7);
    }
    for (; tc < TC; ++tc) { float2 c = ld(tc); K3_STEP(c, tc); }
#undef K3_STEP
    float2 mo; mo.x = m0; mo.y = m1;
    *(float2*)(mem1 + b * NH + h) = mo;
}

// ---------------------------------------------------------------------------
// K4: fc2 sparse gather, one wave per (t,b) row, 4 rows/block.
//   Word i maps h = (i>>1)*128 + 2*bit + (i&1).
// ---------------------------------------------------------------------------
__global__ __launch_bounds__(256) void k4_fc2(const unsigned long long* __restrict__ bits,
                                              const float* __restrict__ W2T,
                                              float* __restrict__ cur2) {
    int row  = blockIdx.x * 4 + (threadIdx.x >> 6);
    int lane = threadIdx.x & 63;
    bool act = lane < NO;
    unsigned long long mv = (lane < 16) ? bits[(size_t)row * 16 + lane] : 0ULL;
    const float* W = W2T + (act ? lane : 0);
    float p0 = 0.f, p1 = 0.f;
#pragma unroll
    for (int i = 0; i < 16; ++i) {
        unsigned long long m = __shfl(mv, i);
        int base = (i >> 1) * 128 + (i & 1);
        while (m) {
            int  b0 = __ffsll(m) - 1;            m &= m - 1;
            bool v1 = m != 0;
            int  b1 = v1 ? __ffsll(m) - 1 : 0;   m &= m - 1;
            float w0 = W[(base + 2 * b0) * NO];
            float w1 = W[(base + 2 * b1) * NO];
            p0 += w0;
            p1 += v1 ? w1 : 0.f;
        }
    }
    if (act) cur2[(size_t)row * NO + lane] = p0 + p1;
}

// ---------------------------------------------------------------------------
// K5: leaky readout + softmax; 128 blocks x 64 threads.
// ---------------------------------------------------------------------------
__global__ __launch_bounds__(64) void k5_readout(const float* __restrict__ cur2,
                                                 float* __restrict__ out_mem,
                                                 float* __restrict__ out_sm) {
    int b = blockIdx.x * 2 + (threadIdx.x >> 5);
    int o = threadIdx.x & 31;
    bool act = o < NO;
    const float* p = cur2 + (size_t)b * NO + (act ? o : 0);
    float mem = 0.f;
    float nxt = p[0];
    for (int t = 0; t < T_STEPS; ++t) {
        float c = nxt;
        if (t + 1 < T_STEPS) nxt = p[(size_t)(t + 1) * BATCH * NO];
        mem = fmaf(BETAF, mem, c);
        float e = act ? __expf(mem) : 0.f;
        float s = e;
#pragma unroll
        for (int off = 16; off; off >>= 1) s += __shfl_xor(s, off, 32);
        if (act) {
            int base = (t * BATCH + b) * NO;
            out_mem[base + o] = mem;
            out_sm[base + o] = __fdividef(e, s);
        }
    }
}

// ---------------------------------------------------------------------------
extern "C" void kernel_launch(void* const* d_in, const int* in_sizes, int n_in,
                              void* d_out, int out_size, void* d_ws, size_t ws_size,
                              hipStream_t stream) {
    const float* spikes = (const float*)d_in[0];   // [250,256,700]
    const float* W1     = (const float*)d_in[1];   // [1024,700]
    const float* W2     = (const float*)d_in[2];   // [20,1024]
    float* out_mem = (float*)d_out;                              // [250,256,20]
    float* out_sm  = out_mem + (size_t)T_STEPS * BATCH * NO;     // [250,256,20]

    char* ws = (char*)d_ws;
    size_t off = 0;
    auto alloc = [&](size_t bytes) -> char* {
        off = (off + 255) & ~(size_t)255;
        char* p = ws + off;
        off += bytes;
        return p;
    };
    float*          W2T  = (float*)alloc((size_t)NH * NO * 4);
    float*          mem1 = (float*)alloc((size_t)BATCH * NH * 4);
    float*          cur2 = (float*)alloc((size_t)T_STEPS * BATCH * NO * 4);
    unsigned short* Bcat = (unsigned short*)alloc((size_t)NH * KCAT * 2);

    // T-chunking: per step need cur1 (1 MB) + Abf (352 KB) + bits (32 KB).
    size_t fixed = (off + 255) & ~(size_t)255;
    size_t rem = ws_size > fixed ? ws_size - fixed : 0;
    size_t per_t = (size_t)BATCH * NH * 4 + (size_t)BATCH * KPAD * 2
                 + (size_t)BATCH * 16 * 8 + 768;
    int TC = (int)(rem / per_t);
    if (TC > T_STEPS) TC = T_STEPS;
    if (TC < 1) TC = 1;
    float*              cur1 = (float*)alloc((size_t)TC * BATCH * NH * 4);
    unsigned short*     Abf  = (unsigned short*)alloc((size_t)TC * BATCH * KPAD * 2);
    unsigned long long* bits = (unsigned long long*)alloc((size_t)TC * BATCH * 16 * 8);

    k0_init<<<(NH * KPAD + 255) / 256, 256, 0, stream>>>(W1, W2, W2T, mem1, Bcat);

    for (int t0 = 0; t0 < T_STEPS; t0 += TC) {
        int tc = T_STEPS - t0 < TC ? T_STEPS - t0 : TC;
        int rows = tc * BATCH;
        k1_cvt<<<(rows * 176 + 255) / 256, 256, 0, stream>>>(
            spikes + (size_t)t0 * BATCH * NI, Abf, rows);
        int nwg = (rows / 256) * 8;   // 256-row m-tiles x 8 n-tiles (128 cols)
        k2_fc1<<<nwg, 512, 0, stream>>>(Abf, Bcat, cur1);
        k3_lif<<<512, 256, 0, stream>>>(cur1, mem1, bits, tc);
        k4_fc2<<<rows / 4, 256, 0, stream>>>(bits, W2T, cur2 + (size_t)t0 * BATCH * NO);
    }

    k5_readout<<<128, 64, 0, stream>>>(cur2, out_mem, out_sm);
}